// Round 3
// baseline (19637.454 us; speedup 1.0000x reference)
//
#include <hip/hip_runtime.h>
#include <hip/hip_cooperative_groups.h>

namespace cg = cooperative_groups;

typedef __attribute__((ext_vector_type(8))) short short8;
typedef __attribute__((ext_vector_type(4))) float f32x4;

static constexpr int B = 256, T = 250, Z = 128, H = 256, D = 512, KMIX = 20, P = 123;
static constexpr int PARAMS_N = B * T * P;
static constexpr int OUT_ZM = PARAMS_N;
static constexpr int OUT_ZL = PARAMS_N + B * Z;

#define DEVI static __device__ __forceinline__

DEVI unsigned short f2bf(float f) {
    unsigned int u = __float_as_uint(f);
    u += 0x7fffu + ((u >> 16) & 1u);
    return (unsigned short)(u >> 16);
}
DEVI float bf2f(unsigned short s) { return __uint_as_float(((unsigned int)s) << 16); }
DEVI float sigm(float x) { return 1.0f / (1.0f + __expf(-x)); }
DEVI float tanh_(float x) {
    x = fminf(fmaxf(x, -15.0f), 15.0f);
    float e = __expf(2.0f * x);
    return (e - 1.0f) / (e + 1.0f);
}

// ---------------- zero-init (ws is poisoned 0xAA every replay) ----------------
__global__ void k_zero(float* c1, float* c2, unsigned short* h1, unsigned short* h2,
                       unsigned short* h1l, unsigned short* h2l, unsigned* ctrs) {
    int i = blockIdx.x * 256 + threadIdx.x;  // 65536 = B*H
    c1[i] = 0.f; c2[i] = 0.f; h1[i] = 0; h2[i] = 0; h1l[i] = 0; h2l[i] = 0;
    if (blockIdx.x == 0 && threadIdx.x < 64) ctrs[threadIdx.x] = 0;
}

// ---------------- weight packing ----------------
// Wh [K=HID][4*HID] fp32 -> hi/lo [4*HID][HID] bf16, rows packed n = 4*d + g
template <int HID>
__global__ void k_pack_whT(const float* __restrict__ Wh, unsigned short* __restrict__ ohi,
                           unsigned short* __restrict__ olo) {
    constexpr int N4 = 4 * HID;
    __shared__ float tile[32][33];
    int c0 = blockIdx.x * 32, k0 = blockIdx.y * 32;
    int tx = threadIdx.x, ty = threadIdx.y;
#pragma unroll
    for (int ii = 0; ii < 4; ii++)
        tile[ty + 8 * ii][tx] = Wh[(size_t)(k0 + ty + 8 * ii) * N4 + c0 + tx];
    __syncthreads();
#pragma unroll
    for (int ii = 0; ii < 4; ii++) {
        int j = ty + 8 * ii;
        int c = c0 + j;
        int g = c / HID, d = c % HID;
        float w = tile[tx][j];
        unsigned short hi = f2bf(w);
        unsigned short lo = f2bf(w - bf2f(hi));
        size_t o = (size_t)(4 * d + g) * HID + k0 + tx;
        ohi[o] = hi;
        olo[o] = lo;
    }
}

// mix_W [512][123] fp32 -> [128][512] bf16 (zero padded cols >=123)
__global__ void k_pack_mix(const float* __restrict__ W, unsigned short* __restrict__ out) {
    int idx = blockIdx.x * 256 + threadIdx.x;  // 128*512
    int n = idx >> 9, k = idx & 511;
    out[idx] = (n < P) ? f2bf(W[(size_t)k * P + n]) : (unsigned short)0;
}

// fp32 column permutation into packed gate order
__global__ void k_pack_cols(const float* __restrict__ in, float* __restrict__ out, int HID, int N4) {
    int idx = blockIdx.x * 256 + threadIdx.x;
    int row = idx / N4, n = idx % N4;
    out[idx] = in[(size_t)row * N4 + (n & 3) * HID + (n >> 2)];
}

// ---------------- cooperative persistent kernel ----------------
struct CoopArgs {
    const float* data;
    const float* eps;
    const unsigned short *whf_hi, *whf_lo, *whb_hi, *whb_lo, *whd_hi, *whd_lo;
    const float *wxp_ef, *wxp_eb, *wxp_dec, *bp_ef, *bp_eb;
    const float *eoW, *eob, *iW, *ib, *dWx, *db;
    unsigned short *hf_hi, *hf_lo, *hb_hi, *hb_lo;  // [2][B][H]
    float *c32_ef, *c32_eb, *c32_d;
    unsigned short* hs_hi;   // [T+1][B][D]
    unsigned short* hlo_pp;  // [2][B][D]
    float *zbuf, *zg;
    float* out;
    unsigned* ctrs;
};

DEVI void group_barrier(unsigned* ctr, unsigned target) {
    __syncthreads();
    if (threadIdx.x == 0) {
        __threadfence();
        __hip_atomic_fetch_add(ctr, 1u, __ATOMIC_RELEASE, __HIP_MEMORY_SCOPE_AGENT);
        while (__hip_atomic_load(ctr, __ATOMIC_ACQUIRE, __HIP_MEMORY_SCOPE_AGENT) < target)
            __builtin_amdgcn_s_sleep(1);
        __threadfence();
    }
    __syncthreads();
}

// pointwise LSTM update; all lanes compute, stores predicated by gate id
DEVI void lstm_point(float v, int g, size_t o, float* __restrict__ c32,
                     unsigned short* __restrict__ hnh, unsigned short* __restrict__ hnl) {
    float s1 = __shfl_xor(v, 1, 64);
    float s2 = __shfl_xor(v, 2, 64);
    float s3 = __shfl_xor(v, 3, 64);
    float gi, gf, gg, go;
    if (g == 0)      { gi = v;  gf = s1; gg = s2; go = s3; }
    else if (g == 1) { gi = s1; gf = v;  gg = s3; go = s2; }
    else if (g == 2) { gi = s2; gf = s3; gg = v;  go = s1; }
    else             { gi = s3; gf = s2; gg = s1; go = v;  }
    float cold = c32[o];
    float cnew = sigm(gf) * cold + sigm(gi) * tanh_(gg);
    float hnew = sigm(go) * tanh_(cnew);
    if (g == 0) {
        c32[o] = cnew;
    } else if (g == 1) {
        hnh[o] = f2bf(hnew);
    } else if (g == 2) {
        unsigned short hi = f2bf(hnew);
        hnl[o] = f2bf(hnew - bf2f(hi));
    }
}

DEVI void run_encoder(const CoopArgs& a) {
    int bid = blockIdx.x;
    int dir = bid >> 7, mb = (bid >> 4) & 7, nb = bid & 15;
    int tid = threadIdx.x, w = tid >> 6, lane = tid & 63, q = lane >> 4, r = lane & 15;
    int m0 = mb * 32;
    int n0 = nb * 64 + w * 16;
    const unsigned short* __restrict__ whi = dir ? a.whb_hi : a.whf_hi;
    const unsigned short* __restrict__ wlo = dir ? a.whb_lo : a.whf_lo;
    const float* __restrict__ wxp = dir ? a.wxp_eb : a.wxp_ef;
    const float* __restrict__ bp = dir ? a.bp_eb : a.bp_ef;
    unsigned short* __restrict__ hhi = dir ? a.hb_hi : a.hf_hi;
    unsigned short* __restrict__ hlo = dir ? a.hb_lo : a.hf_lo;
    float* __restrict__ c32 = dir ? a.c32_eb : a.c32_ef;
    unsigned* ctr = a.ctrs + dir * 8 + mb;

    int c = n0 + r;
    int g = r & 3, d = c >> 2;

    short8 bh[8], bl[8];
#pragma unroll
    for (int ki = 0; ki < 8; ki++) {
        bh[ki] = *(const short8*)(whi + (size_t)c * H + ki * 32 + q * 8);
        bl[ki] = *(const short8*)(wlo + (size_t)c * H + ki * 32 + q * 8);
    }
    float wx0 = wxp[0 * 1024 + c], wx1 = wxp[1 * 1024 + c], wx2 = wxp[2 * 1024 + c];
    float wx3 = wxp[3 * 1024 + c], wx4 = wxp[4 * 1024 + c];
    float bias = bp[c];

    for (int t = 0; t < T; t++) {
        int pi = t & 1, po = 1 - pi;
        const unsigned short* __restrict__ hph = hhi + (size_t)pi * B * H;
        const unsigned short* __restrict__ hpl = hlo + (size_t)pi * B * H;
        f32x4 acc0 = {0.f, 0.f, 0.f, 0.f}, acc1 = {0.f, 0.f, 0.f, 0.f};
#pragma unroll
        for (int ki = 0; ki < 8; ki++) {
            int kb = ki * 32 + q * 8;
            short8 a0h = *(const short8*)(hph + (size_t)(m0 + r) * H + kb);
            short8 a1h = *(const short8*)(hph + (size_t)(m0 + 16 + r) * H + kb);
            short8 a0l = *(const short8*)(hpl + (size_t)(m0 + r) * H + kb);
            short8 a1l = *(const short8*)(hpl + (size_t)(m0 + 16 + r) * H + kb);
            acc0 = __builtin_amdgcn_mfma_f32_16x16x32_bf16(a0h, bh[ki], acc0, 0, 0, 0);
            acc1 = __builtin_amdgcn_mfma_f32_16x16x32_bf16(a1h, bh[ki], acc1, 0, 0, 0);
            acc0 = __builtin_amdgcn_mfma_f32_16x16x32_bf16(a0l, bh[ki], acc0, 0, 0, 0);
            acc1 = __builtin_amdgcn_mfma_f32_16x16x32_bf16(a1l, bh[ki], acc1, 0, 0, 0);
            acc0 = __builtin_amdgcn_mfma_f32_16x16x32_bf16(a0h, bl[ki], acc0, 0, 0, 0);
            acc1 = __builtin_amdgcn_mfma_f32_16x16x32_bf16(a1h, bl[ki], acc1, 0, 0, 0);
        }
        int tt = dir ? (250 - t) : (1 + t);
        const float* xbase = a.data + (size_t)tt * 5;
        unsigned short* __restrict__ hnh = hhi + (size_t)po * B * H;
        unsigned short* __restrict__ hnl = hlo + (size_t)po * B * H;
#pragma unroll
        for (int mi = 0; mi < 2; mi++) {
            f32x4 acc = mi ? acc1 : acc0;
#pragma unroll
            for (int rr = 0; rr < 4; rr++) {
                int b = m0 + mi * 16 + q * 4 + rr;
                const float* xr = xbase + (size_t)b * (5 * (T + 1));
                float v = acc[rr] + bias + xr[0] * wx0 + xr[1] * wx1 + xr[2] * wx2 +
                          xr[3] * wx3 + xr[4] * wx4;
                lstm_point(v, g, (size_t)b * H + d, c32, hnh, hnl);
            }
        }
        group_barrier(ctr, 16u * (unsigned)(t + 1));
    }
}

DEVI void run_decoder(const CoopArgs& a) {
    int bid = blockIdx.x;
    int mb = bid >> 5, nb = bid & 31;
    int tid = threadIdx.x, w = tid >> 6, lane = tid & 63, q = lane >> 4, r = lane & 15;
    int m0 = mb * 32;
    int n0 = nb * 64 + w * 16;
    unsigned* ctr = a.ctrs + 16 + mb;

    int c = n0 + r;
    int g = r & 3, d = c >> 2;

    short8 bh[16], bl[16];
#pragma unroll
    for (int ki = 0; ki < 16; ki++) {
        bh[ki] = *(const short8*)(a.whd_hi + (size_t)c * D + ki * 32 + q * 8);
        bl[ki] = *(const short8*)(a.whd_lo + (size_t)c * D + ki * 32 + q * 8);
    }
    float wx0 = a.wxp_dec[0 * 2048 + c], wx1 = a.wxp_dec[1 * 2048 + c], wx2 = a.wxp_dec[2 * 2048 + c];
    float wx3 = a.wxp_dec[3 * 2048 + c], wx4 = a.wxp_dec[4 * 2048 + c];
    float zgc[2][4];
#pragma unroll
    for (int mi = 0; mi < 2; mi++)
#pragma unroll
        for (int rr = 0; rr < 4; rr++) {
            int b = m0 + mi * 16 + q * 4 + rr;
            zgc[mi][rr] = a.zg[(size_t)b * 2048 + c];
        }

    for (int t = 0; t < T; t++) {
        int pi = t & 1, po = 1 - pi;
        const unsigned short* __restrict__ hph = a.hs_hi + (size_t)t * B * D;
        const unsigned short* __restrict__ hpl = a.hlo_pp + (size_t)pi * B * D;
        f32x4 acc0 = {0.f, 0.f, 0.f, 0.f}, acc1 = {0.f, 0.f, 0.f, 0.f};
#pragma unroll
        for (int ki = 0; ki < 16; ki++) {
            int kb = ki * 32 + q * 8;
            short8 a0h = *(const short8*)(hph + (size_t)(m0 + r) * D + kb);
            short8 a1h = *(const short8*)(hph + (size_t)(m0 + 16 + r) * D + kb);
            short8 a0l = *(const short8*)(hpl + (size_t)(m0 + r) * D + kb);
            short8 a1l = *(const short8*)(hpl + (size_t)(m0 + 16 + r) * D + kb);
            acc0 = __builtin_amdgcn_mfma_f32_16x16x32_bf16(a0h, bh[ki], acc0, 0, 0, 0);
            acc1 = __builtin_amdgcn_mfma_f32_16x16x32_bf16(a1h, bh[ki], acc1, 0, 0, 0);
            acc0 = __builtin_amdgcn_mfma_f32_16x16x32_bf16(a0l, bh[ki], acc0, 0, 0, 0);
            acc1 = __builtin_amdgcn_mfma_f32_16x16x32_bf16(a1l, bh[ki], acc1, 0, 0, 0);
            acc0 = __builtin_amdgcn_mfma_f32_16x16x32_bf16(a0h, bl[ki], acc0, 0, 0, 0);
            acc1 = __builtin_amdgcn_mfma_f32_16x16x32_bf16(a1h, bl[ki], acc1, 0, 0, 0);
        }
        const float* xbase = a.data + (size_t)t * 5;
        unsigned short* __restrict__ hnh = a.hs_hi + (size_t)(t + 1) * B * D;
        unsigned short* __restrict__ hnl = a.hlo_pp + (size_t)po * B * D;
#pragma unroll
        for (int mi = 0; mi < 2; mi++) {
            f32x4 acc = mi ? acc1 : acc0;
#pragma unroll
            for (int rr = 0; rr < 4; rr++) {
                int b = m0 + mi * 16 + q * 4 + rr;
                const float* xr = xbase + (size_t)b * (5 * (T + 1));
                float v = acc[rr] + zgc[mi][rr] + xr[0] * wx0 + xr[1] * wx1 + xr[2] * wx2 +
                          xr[3] * wx3 + xr[4] * wx4;
                lstm_point(v, g, (size_t)b * D + d, a.c32_d, hnh, hnl);
            }
        }
        group_barrier(ctr, 32u * (unsigned)(t + 1));
    }
}

DEVI void run_encout(const CoopArgs& a, float* smem) {
    int b = blockIdx.x, tid = threadIdx.x;
    if (tid < 128) {
        smem[tid]       = bf2f(a.hf_hi[(size_t)b * H + tid])       + bf2f(a.hf_lo[(size_t)b * H + tid]);
        smem[tid + 128] = bf2f(a.hf_hi[(size_t)b * H + tid + 128]) + bf2f(a.hf_lo[(size_t)b * H + tid + 128]);
        smem[tid + 256] = bf2f(a.hb_hi[(size_t)b * H + tid])       + bf2f(a.hb_lo[(size_t)b * H + tid]);
        smem[tid + 384] = bf2f(a.hb_hi[(size_t)b * H + tid + 128]) + bf2f(a.hb_lo[(size_t)b * H + tid + 128]);
    }
    __syncthreads();
    if (tid < 128) {
        float mean = a.eob[tid], lv = a.eob[Z + tid];
        for (int k = 0; k < 2 * H; k++) {
            float h = smem[k];
            mean += h * a.eoW[(size_t)k * 2 * Z + tid];
            lv += h * a.eoW[(size_t)k * 2 * Z + Z + tid];
        }
        float z = mean + __expf(0.5f * lv) * a.eps[(size_t)b * Z + tid];
        a.out[OUT_ZM + (size_t)b * Z + tid] = mean;
        a.out[OUT_ZL + (size_t)b * Z + tid] = lv;
        a.zbuf[(size_t)b * Z + tid] = z;
    }
    __syncthreads();
}

DEVI void run_init_zg(const CoopArgs& a, float* smem) {
    int bid = blockIdx.x, tid = threadIdx.x;
    if (bid < 64) {
        int cc = (bid & 3) * 256 + tid;
        int b0 = (bid >> 2) * 16;
        for (int i = tid; i < 16 * Z; i += 256)
            smem[i] = a.zbuf[(size_t)(b0 + (i >> 7)) * Z + (i & 127)];
        __syncthreads();
        float acc[16];
        float bias = a.ib[cc];
#pragma unroll
        for (int bb = 0; bb < 16; bb++) acc[bb] = bias;
        for (int k = 0; k < Z; k++) {
            float wv = a.iW[(size_t)k * 1024 + cc];
#pragma unroll
            for (int bb = 0; bb < 16; bb++) acc[bb] += smem[bb * 128 + k] * wv;
        }
        for (int bb = 0; bb < 16; bb++) {
            float v = tanh_(acc[bb]);
            int b = b0 + bb;
            if (cc < D) {
                unsigned short hi = f2bf(v);
                a.hs_hi[(size_t)b * D + cc] = hi;
                a.hlo_pp[(size_t)b * D + cc] = f2bf(v - bf2f(hi));
            } else {
                a.c32_d[(size_t)b * D + (cc - D)] = v;
            }
        }
    } else if (bid < 192) {
        int bid2 = bid - 64;
        int cc = (bid2 & 7) * 256 + tid;
        int b0 = (bid2 >> 3) * 16;
        for (int i = tid; i < 16 * Z; i += 256)
            smem[i] = a.zbuf[(size_t)(b0 + (i >> 7)) * Z + (i & 127)];
        __syncthreads();
        float acc[16];
        float db_c = a.db[cc];
#pragma unroll
        for (int bb = 0; bb < 16; bb++) acc[bb] = db_c;
        for (int k = 0; k < Z; k++) {
            float wv = a.dWx[(size_t)(5 + k) * 2048 + cc];
#pragma unroll
            for (int bb = 0; bb < 16; bb++) acc[bb] += smem[bb * 128 + k] * wv;
        }
        int n = 4 * (cc & 511) + (cc >> 9);
#pragma unroll
        for (int bb = 0; bb < 16; bb++) a.zg[(size_t)(b0 + bb) * 2048 + n] = acc[bb];
    }
    __syncthreads();
}

__global__ __launch_bounds__(256, 1) void k_coop(CoopArgs a) {
    __shared__ float smem[2048];
    run_encoder(a);
    __threadfence();
    cg::this_grid().sync();
    run_encout(a, smem);
    __threadfence();
    cg::this_grid().sync();
    run_init_zg(a, smem);
    __threadfence();
    cg::this_grid().sync();
    run_decoder(a);
}

// ---------------- mix GEMM ----------------
__global__ __launch_bounds__(256) void k_mix(const unsigned short* __restrict__ hs,
                                             const unsigned short* __restrict__ mixwt,
                                             const float* __restrict__ mb, float* __restrict__ dout) {
    int tid = threadIdx.x, wave = tid >> 6, lane = tid & 63, q = lane >> 4, r = lane & 15;
    int m0 = blockIdx.y * 64 + (wave >> 1) * 32;
    int n0 = blockIdx.x * 64 + (wave & 1) * 32;
    const unsigned short* A = hs + (size_t)B * D;
    f32x4 acc[2][2];
#pragma unroll
    for (int mi = 0; mi < 2; mi++)
#pragma unroll
        for (int ni = 0; ni < 2; ni++) acc[mi][ni] = {0.f, 0.f, 0.f, 0.f};
#pragma unroll 4
    for (int kk = 0; kk < D; kk += 32) {
        int kb = kk + q * 8;
        short8 a0 = *(const short8*)(A + (size_t)(m0 + r) * D + kb);
        short8 a1 = *(const short8*)(A + (size_t)(m0 + 16 + r) * D + kb);
        short8 b0 = *(const short8*)(mixwt + (size_t)(n0 + r) * D + kb);
        short8 b1 = *(const short8*)(mixwt + (size_t)(n0 + 16 + r) * D + kb);
        acc[0][0] = __builtin_amdgcn_mfma_f32_16x16x32_bf16(a0, b0, acc[0][0], 0, 0, 0);
        acc[0][1] = __builtin_amdgcn_mfma_f32_16x16x32_bf16(a0, b1, acc[0][1], 0, 0, 0);
        acc[1][0] = __builtin_amdgcn_mfma_f32_16x16x32_bf16(a1, b0, acc[1][0], 0, 0, 0);
        acc[1][1] = __builtin_amdgcn_mfma_f32_16x16x32_bf16(a1, b1, acc[1][1], 0, 0, 0);
    }
#pragma unroll
    for (int ni = 0; ni < 2; ni++) {
        int ncol = n0 + ni * 16 + r;
        if (ncol < P) {
            float bias = mb[ncol];
#pragma unroll
            for (int mi = 0; mi < 2; mi++) {
#pragma unroll
                for (int rr = 0; rr < 4; rr++) {
                    int m = m0 + mi * 16 + q * 4 + rr;
                    int b = m & 255, t = m >> 8;
                    dout[((size_t)b * T + t) * P + ncol] = acc[mi][ni][rr] + bias;
                }
            }
        }
    }
}

// ---------------- per-row epilogue ----------------
__global__ void k_post(float* __restrict__ dout) {
    __shared__ float row[P];
    int rid = blockIdx.x;
    int tid = threadIdx.x;
    float* base = dout + (size_t)rid * P;
    float v = 0.f;
    if (tid < P) { v = base[tid]; row[tid] = v; }
    __syncthreads();
    if (tid < P) {
        float o;
        if (tid < KMIX) {
            float mx = row[0];
            for (int i = 1; i < KMIX; i++) mx = fmaxf(mx, row[i]);
            float sm = 0.f;
            for (int i = 0; i < KMIX; i++) sm += __expf(row[i] - mx);
            o = __expf(v - mx) / sm;
        } else if (tid < 3 * KMIX) o = v;
        else if (tid < 5 * KMIX) o = __expf(v);
        else if (tid < 6 * KMIX) o = tanh_(v);
        else o = v;
        base[tid] = o;
    }
}

extern "C" void kernel_launch(void* const* d_in, const int* in_sizes, int n_in,
                              void* d_out, int out_size, void* d_ws, size_t ws_size,
                              hipStream_t stream) {
    const float* data = (const float*)d_in[0];
    const float* eps  = (const float*)d_in[1];
    const float* eWxf = (const float*)d_in[2];
    const float* eWhf = (const float*)d_in[3];
    const float* ebf  = (const float*)d_in[4];
    const float* eWxb = (const float*)d_in[5];
    const float* eWhb = (const float*)d_in[6];
    const float* ebb  = (const float*)d_in[7];
    const float* eoW  = (const float*)d_in[8];
    const float* eob  = (const float*)d_in[9];
    const float* iW   = (const float*)d_in[10];
    const float* ib   = (const float*)d_in[11];
    const float* dWx  = (const float*)d_in[12];
    const float* dWh  = (const float*)d_in[13];
    const float* db   = (const float*)d_in[14];
    const float* mW   = (const float*)d_in[15];
    const float* mb   = (const float*)d_in[16];
    float* out = (float*)d_out;

    char* base = (char*)d_ws;
    size_t off = 0;
    auto alloc = [&](size_t bytes) -> char* {
        off = (off + 255) & ~(size_t)255;
        char* p = base + off;
        off += bytes;
        return p;
    };
    unsigned short* whd_hi = (unsigned short*)alloc((size_t)2048 * 512 * 2);
    unsigned short* whd_lo = (unsigned short*)alloc((size_t)2048 * 512 * 2);
    unsigned short* whf_hi = (unsigned short*)alloc((size_t)1024 * 256 * 2);
    unsigned short* whf_lo = (unsigned short*)alloc((size_t)1024 * 256 * 2);
    unsigned short* whb_hi = (unsigned short*)alloc((size_t)1024 * 256 * 2);
    unsigned short* whb_lo = (unsigned short*)alloc((size_t)1024 * 256 * 2);
    unsigned short* mixwt  = (unsigned short*)alloc((size_t)128 * 512 * 2);
    float* wxp_dec = (float*)alloc((size_t)5 * 2048 * 4);
    float* wxp_ef  = (float*)alloc((size_t)5 * 1024 * 4);
    float* wxp_eb  = (float*)alloc((size_t)5 * 1024 * 4);
    float* bp_ef   = (float*)alloc((size_t)1024 * 4);
    float* bp_eb   = (float*)alloc((size_t)1024 * 4);
    unsigned short* hf_hi = (unsigned short*)alloc((size_t)2 * B * H * 2);
    unsigned short* hf_lo = (unsigned short*)alloc((size_t)2 * B * H * 2);
    unsigned short* hb_hi = (unsigned short*)alloc((size_t)2 * B * H * 2);
    unsigned short* hb_lo = (unsigned short*)alloc((size_t)2 * B * H * 2);
    float* c32_ef = (float*)alloc((size_t)B * H * 4);
    float* c32_eb = (float*)alloc((size_t)B * H * 4);
    float* c32_d  = (float*)alloc((size_t)B * D * 4);
    unsigned short* hs_hi = (unsigned short*)alloc((size_t)(T + 1) * B * D * 2);
    unsigned short* hlo_pp = (unsigned short*)alloc((size_t)2 * B * D * 2);
    float* zbuf = (float*)alloc((size_t)B * Z * 4);
    float* zg   = (float*)alloc((size_t)B * 2048 * 4);
    unsigned* ctrs = (unsigned*)alloc(64 * 4);
    (void)ws_size; (void)in_sizes; (void)n_in; (void)out_size;

    k_zero<<<256, 256, 0, stream>>>(c32_ef, c32_eb, hf_hi, hb_hi, hf_lo, hb_lo, ctrs);
    k_pack_whT<512><<<dim3(64, 16), dim3(32, 8), 0, stream>>>(dWh, whd_hi, whd_lo);
    k_pack_whT<256><<<dim3(32, 8), dim3(32, 8), 0, stream>>>(eWhf, whf_hi, whf_lo);
    k_pack_whT<256><<<dim3(32, 8), dim3(32, 8), 0, stream>>>(eWhb, whb_hi, whb_lo);
    k_pack_mix<<<256, 256, 0, stream>>>(mW, mixwt);
    k_pack_cols<<<40, 256, 0, stream>>>(dWx, wxp_dec, 512, 2048);
    k_pack_cols<<<20, 256, 0, stream>>>(eWxf, wxp_ef, 256, 1024);
    k_pack_cols<<<20, 256, 0, stream>>>(eWxb, wxp_eb, 256, 1024);
    k_pack_cols<<<4, 256, 0, stream>>>(ebf, bp_ef, 256, 1024);
    k_pack_cols<<<4, 256, 0, stream>>>(ebb, bp_eb, 256, 1024);

    CoopArgs ca;
    ca.data = data; ca.eps = eps;
    ca.whf_hi = whf_hi; ca.whf_lo = whf_lo; ca.whb_hi = whb_hi; ca.whb_lo = whb_lo;
    ca.whd_hi = whd_hi; ca.whd_lo = whd_lo;
    ca.wxp_ef = wxp_ef; ca.wxp_eb = wxp_eb; ca.wxp_dec = wxp_dec;
    ca.bp_ef = bp_ef; ca.bp_eb = bp_eb;
    ca.eoW = eoW; ca.eob = eob; ca.iW = iW; ca.ib = ib; ca.dWx = dWx; ca.db = db;
    ca.hf_hi = hf_hi; ca.hf_lo = hf_lo; ca.hb_hi = hb_hi; ca.hb_lo = hb_lo;
    ca.c32_ef = c32_ef; ca.c32_eb = c32_eb; ca.c32_d = c32_d;
    ca.hs_hi = hs_hi; ca.hlo_pp = hlo_pp;
    ca.zbuf = zbuf; ca.zg = zg; ca.out = out; ca.ctrs = ctrs;

    void* kp[] = { &ca };
    hipLaunchCooperativeKernel((void*)k_coop, dim3(256), dim3(256), kp, 0, stream);

    k_mix<<<dim3(2, 1000), 256, 0, stream>>>(hs_hi, mixwt, mb, out);
    k_post<<<64000, 128, 0, stream>>>(out);
}

// Round 4
// 10624.451 us; speedup vs baseline: 1.8483x; 1.8483x over previous
//
#include <hip/hip_runtime.h>
#include <hip/hip_cooperative_groups.h>

namespace cg = cooperative_groups;

typedef __attribute__((ext_vector_type(8))) short short8;
typedef __attribute__((ext_vector_type(4))) float f32x4;

static constexpr int B = 256, T = 250, Z = 128, H = 256, D = 512, KMIX = 20, P = 123;
static constexpr int PARAMS_N = B * T * P;
static constexpr int OUT_ZM = PARAMS_N;
static constexpr int OUT_ZL = PARAMS_N + B * Z;

#define DEVI static __device__ __forceinline__

DEVI unsigned short f2bf(float f) {
    unsigned int u = __float_as_uint(f);
    u += 0x7fffu + ((u >> 16) & 1u);
    return (unsigned short)(u >> 16);
}
DEVI float bf2f(unsigned short s) { return __uint_as_float(((unsigned int)s) << 16); }
DEVI float sigm(float x) { return 1.0f / (1.0f + __expf(-x)); }
DEVI float tanh_(float x) {
    x = fminf(fmaxf(x, -15.0f), 15.0f);
    float e = __expf(2.0f * x);
    return (e - 1.0f) / (e + 1.0f);
}

// ---------------- zero-init (ws is poisoned 0xAA every replay) ----------------
__global__ void k_zero(unsigned short* h1, unsigned short* h2,
                       unsigned short* h1l, unsigned short* h2l, unsigned* ctrs) {
    int i = blockIdx.x * 256 + threadIdx.x;  // 65536 = B*H (slot 0 of each ping-pong)
    h1[i] = 0; h2[i] = 0; h1l[i] = 0; h2l[i] = 0;
    if (blockIdx.x == 0 && threadIdx.x < 64) ctrs[threadIdx.x] = 0;
}

// ---------------- weight packing ----------------
// Wh [K=HID][4*HID] fp32 -> hi/lo [4*HID][HID] bf16, rows packed n = 4*d + g
template <int HID>
__global__ void k_pack_whT(const float* __restrict__ Wh, unsigned short* __restrict__ ohi,
                           unsigned short* __restrict__ olo) {
    constexpr int N4 = 4 * HID;
    __shared__ float tile[32][33];
    int c0 = blockIdx.x * 32, k0 = blockIdx.y * 32;
    int tx = threadIdx.x, ty = threadIdx.y;
#pragma unroll
    for (int ii = 0; ii < 4; ii++)
        tile[ty + 8 * ii][tx] = Wh[(size_t)(k0 + ty + 8 * ii) * N4 + c0 + tx];
    __syncthreads();
#pragma unroll
    for (int ii = 0; ii < 4; ii++) {
        int j = ty + 8 * ii;
        int c = c0 + j;
        int g = c / HID, d = c % HID;
        float w = tile[tx][j];
        unsigned short hi = f2bf(w);
        unsigned short lo = f2bf(w - bf2f(hi));
        size_t o = (size_t)(4 * d + g) * HID + k0 + tx;
        ohi[o] = hi;
        olo[o] = lo;
    }
}

// mix_W [512][123] fp32 -> [128][512] bf16 (zero padded cols >=123)
__global__ void k_pack_mix(const float* __restrict__ W, unsigned short* __restrict__ out) {
    int idx = blockIdx.x * 256 + threadIdx.x;  // 128*512
    int n = idx >> 9, k = idx & 511;
    out[idx] = (n < P) ? f2bf(W[(size_t)k * P + n]) : (unsigned short)0;
}

// fp32 column permutation into packed gate order
__global__ void k_pack_cols(const float* __restrict__ in, float* __restrict__ out, int HID, int N4) {
    int idx = blockIdx.x * 256 + threadIdx.x;
    int row = idx / N4, n = idx % N4;
    out[idx] = in[(size_t)row * N4 + (n & 3) * HID + (n >> 2)];
}

// ---------------- cooperative persistent kernel ----------------
struct CoopArgs {
    const float* data;
    const float* eps;
    const unsigned short *whf_hi, *whf_lo, *whb_hi, *whb_lo, *whd_hi, *whd_lo;
    const float *wxp_ef, *wxp_eb, *wxp_dec, *bp_ef, *bp_eb;
    const float *eoW, *eob, *iW, *ib, *dWx, *db;
    unsigned short *hf_hi, *hf_lo, *hb_hi, *hb_lo;  // [2][B][H]
    float* c32_d;
    unsigned short* hs_hi;   // [T+1][B][D]
    unsigned short* hlo_pp;  // [2][B][D]
    float *zbuf, *zg;
    float* out;
    unsigned* ctrs;
};

// Barrier among a group of blocks. Writers' h-stores are agent-scope write-through
// atomics and each wave drains vmcnt at __syncthreads, so the L2 stays clean:
// the RELEASE here is cheap, and ONE acquire fence (buffer_inv) per step suffices.
DEVI void group_barrier(unsigned* ctr, unsigned target) {
    __syncthreads();
    if (threadIdx.x == 0) {
        __hip_atomic_fetch_add(ctr, 1u, __ATOMIC_RELEASE, __HIP_MEMORY_SCOPE_AGENT);
        while (__hip_atomic_load(ctr, __ATOMIC_RELAXED, __HIP_MEMORY_SCOPE_AGENT) < target)
            __builtin_amdgcn_s_sleep(4);
        __builtin_amdgcn_fence(__ATOMIC_ACQUIRE, "agent");
    }
    __syncthreads();
}

// quad-shuffle gate gather + pointwise update; c lives in a register (quad-redundant)
DEVI float lstm_quad(float v, int g, float& c) {
    float s1 = __shfl_xor(v, 1, 64);
    float s2 = __shfl_xor(v, 2, 64);
    float s3 = __shfl_xor(v, 3, 64);
    float gi, gf, gg, go;
    if (g == 0)      { gi = v;  gf = s1; gg = s2; go = s3; }
    else if (g == 1) { gi = s1; gf = v;  gg = s3; go = s2; }
    else if (g == 2) { gi = s2; gf = s3; gg = v;  go = s1; }
    else             { gi = s3; gf = s2; gg = s1; go = v;  }
    float cnew = sigm(gf) * c + sigm(gi) * tanh_(gg);
    c = cnew;
    return sigm(go) * tanh_(cnew);
}

// packed 4B agent-scope write-through stores of (hi_d, hi_{d+1}) and (lo_d, lo_{d+1})
DEVI void store_h_pair(float hnew, int r, unsigned short* __restrict__ hnh,
                       unsigned short* __restrict__ hnl, size_t o_even) {
    unsigned short hi = f2bf(hnew);
    float lo = hnew - bf2f(hi);
    float hp = __shfl_xor(hnew, 4, 64);   // partner d (xor of bit2 of r flips d lsb)
    unsigned short hip = f2bf(hp);
    float lop = hp - bf2f(hip);
    if ((r & 7) == 0) {
        unsigned pk = (unsigned)hi | ((unsigned)hip << 16);
        __hip_atomic_store((unsigned*)(hnh + o_even), pk, __ATOMIC_RELAXED, __HIP_MEMORY_SCOPE_AGENT);
    } else if ((r & 7) == 1) {
        unsigned pk = (unsigned)f2bf(lo) | ((unsigned)f2bf(lop) << 16);
        __hip_atomic_store((unsigned*)(hnl + o_even), pk, __ATOMIC_RELAXED, __HIP_MEMORY_SCOPE_AGENT);
    }
}

DEVI void run_encoder(const CoopArgs& a, float (*smx)[160]) {
    int bid = blockIdx.x;
    int dir = bid >> 7, mb = (bid >> 4) & 7, nb = bid & 15;
    int tid = threadIdx.x, w = tid >> 6, lane = tid & 63, q = lane >> 4, r = lane & 15;
    int m0 = mb * 32;
    const unsigned short* __restrict__ whi = dir ? a.whb_hi : a.whf_hi;
    const unsigned short* __restrict__ wlo = dir ? a.whb_lo : a.whf_lo;
    const float* __restrict__ wxp = dir ? a.wxp_eb : a.wxp_ef;
    const float* __restrict__ bp = dir ? a.bp_eb : a.bp_ef;
    unsigned short* __restrict__ hhi = dir ? a.hb_hi : a.hf_hi;
    unsigned short* __restrict__ hlo = dir ? a.hb_lo : a.hf_lo;
    unsigned* ctr = a.ctrs + dir * 8 + mb;

    int c = nb * 64 + w * 16 + r;
    int g = r & 3, d = c >> 2;
    size_t d_even = (size_t)(d & ~1);

    short8 bh[8], bl[8];
#pragma unroll
    for (int ki = 0; ki < 8; ki++) {
        bh[ki] = *(const short8*)(whi + (size_t)c * H + ki * 32 + q * 8);
        bl[ki] = *(const short8*)(wlo + (size_t)c * H + ki * 32 + q * 8);
    }
    float wx0 = wxp[0 * 1024 + c], wx1 = wxp[1 * 1024 + c], wx2 = wxp[2 * 1024 + c];
    float wx3 = wxp[3 * 1024 + c], wx4 = wxp[4 * 1024 + c];
    float bias = bp[c];
    float creg[2][4];
#pragma unroll
    for (int mi = 0; mi < 2; mi++)
#pragma unroll
        for (int rr = 0; rr < 4; rr++) creg[mi][rr] = 0.f;

    // stage x(t=0) into LDS buf 0
    {
        int tt0 = dir ? 250 : 1;
        if (tid < 32) {
            const float* p = a.data + (size_t)(m0 + tid) * (5 * (T + 1)) + (size_t)tt0 * 5;
#pragma unroll
            for (int j = 0; j < 5; j++) smx[0][tid * 5 + j] = p[j];
        }
    }
    __syncthreads();

    for (int t = 0; t < T; t++) {
        int pi = t & 1, po = 1 - pi;
        const unsigned short* __restrict__ hph = hhi + (size_t)pi * B * H;
        const unsigned short* __restrict__ hpl = hlo + (size_t)pi * B * H;
        f32x4 acc0 = {0.f, 0.f, 0.f, 0.f}, acc1 = {0.f, 0.f, 0.f, 0.f};
#pragma unroll
        for (int ki = 0; ki < 8; ki++) {
            int kb = ki * 32 + q * 8;
            short8 a0h = *(const short8*)(hph + (size_t)(m0 + r) * H + kb);
            short8 a1h = *(const short8*)(hph + (size_t)(m0 + 16 + r) * H + kb);
            short8 a0l = *(const short8*)(hpl + (size_t)(m0 + r) * H + kb);
            short8 a1l = *(const short8*)(hpl + (size_t)(m0 + 16 + r) * H + kb);
            acc0 = __builtin_amdgcn_mfma_f32_16x16x32_bf16(a0h, bh[ki], acc0, 0, 0, 0);
            acc1 = __builtin_amdgcn_mfma_f32_16x16x32_bf16(a1h, bh[ki], acc1, 0, 0, 0);
            acc0 = __builtin_amdgcn_mfma_f32_16x16x32_bf16(a0l, bh[ki], acc0, 0, 0, 0);
            acc1 = __builtin_amdgcn_mfma_f32_16x16x32_bf16(a1l, bh[ki], acc1, 0, 0, 0);
            acc0 = __builtin_amdgcn_mfma_f32_16x16x32_bf16(a0h, bl[ki], acc0, 0, 0, 0);
            acc1 = __builtin_amdgcn_mfma_f32_16x16x32_bf16(a1h, bl[ki], acc1, 0, 0, 0);
        }
        // prefetch x(t+1) into the other LDS buffer (overlaps epilogue)
        if (t + 1 < T && tid < 32) {
            int ttn = dir ? (249 - t) : (2 + t);
            const float* p = a.data + (size_t)(m0 + tid) * (5 * (T + 1)) + (size_t)ttn * 5;
#pragma unroll
            for (int j = 0; j < 5; j++) smx[(t + 1) & 1][tid * 5 + j] = p[j];
        }
        unsigned short* __restrict__ hnh = hhi + (size_t)po * B * H;
        unsigned short* __restrict__ hnl = hlo + (size_t)po * B * H;
        const float* xb = smx[t & 1];
#pragma unroll
        for (int mi = 0; mi < 2; mi++) {
            f32x4 acc = mi ? acc1 : acc0;
#pragma unroll
            for (int rr = 0; rr < 4; rr++) {
                int brow = mi * 16 + q * 4 + rr;
                float v = acc[rr] + bias + xb[brow * 5 + 0] * wx0 + xb[brow * 5 + 1] * wx1 +
                          xb[brow * 5 + 2] * wx2 + xb[brow * 5 + 3] * wx3 + xb[brow * 5 + 4] * wx4;
                float hnew = lstm_quad(v, g, creg[mi][rr]);
                store_h_pair(hnew, r, hnh, hnl, (size_t)(m0 + brow) * H + d_even);
            }
        }
        group_barrier(ctr, 16u * (unsigned)(t + 1));
    }
}

DEVI void run_decoder(const CoopArgs& a, float (*smx)[160]) {
    int bid = blockIdx.x;
    int mb = bid >> 5, nb = bid & 31;
    int tid = threadIdx.x, w = tid >> 6, lane = tid & 63, q = lane >> 4, r = lane & 15;
    int m0 = mb * 32;
    unsigned* ctr = a.ctrs + 16 + mb;

    int c = nb * 64 + w * 16 + r;
    int g = r & 3, d = c >> 2;
    size_t d_even = (size_t)(d & ~1);

    short8 bh[16], bl[16];
#pragma unroll
    for (int ki = 0; ki < 16; ki++) {
        bh[ki] = *(const short8*)(a.whd_hi + (size_t)c * D + ki * 32 + q * 8);
        bl[ki] = *(const short8*)(a.whd_lo + (size_t)c * D + ki * 32 + q * 8);
    }
    float wx0 = a.wxp_dec[0 * 2048 + c], wx1 = a.wxp_dec[1 * 2048 + c], wx2 = a.wxp_dec[2 * 2048 + c];
    float wx3 = a.wxp_dec[3 * 2048 + c], wx4 = a.wxp_dec[4 * 2048 + c];
    float zgc[2][4], creg[2][4];
#pragma unroll
    for (int mi = 0; mi < 2; mi++)
#pragma unroll
        for (int rr = 0; rr < 4; rr++) {
            int b = m0 + mi * 16 + q * 4 + rr;
            zgc[mi][rr] = a.zg[(size_t)b * 2048 + c];
            creg[mi][rr] = a.c32_d[(size_t)b * D + d];
        }

    if (tid < 32) {
        const float* p = a.data + (size_t)(m0 + tid) * (5 * (T + 1));
#pragma unroll
        for (int j = 0; j < 5; j++) smx[0][tid * 5 + j] = p[j];
    }
    __syncthreads();

    for (int t = 0; t < T; t++) {
        int pi = t & 1, po = 1 - pi;
        const unsigned short* __restrict__ hph = a.hs_hi + (size_t)t * B * D;
        const unsigned short* __restrict__ hpl = a.hlo_pp + (size_t)pi * B * D;
        f32x4 acc0 = {0.f, 0.f, 0.f, 0.f}, acc1 = {0.f, 0.f, 0.f, 0.f};
#pragma unroll
        for (int ki = 0; ki < 16; ki++) {
            int kb = ki * 32 + q * 8;
            short8 a0h = *(const short8*)(hph + (size_t)(m0 + r) * D + kb);
            short8 a1h = *(const short8*)(hph + (size_t)(m0 + 16 + r) * D + kb);
            short8 a0l = *(const short8*)(hpl + (size_t)(m0 + r) * D + kb);
            short8 a1l = *(const short8*)(hpl + (size_t)(m0 + 16 + r) * D + kb);
            acc0 = __builtin_amdgcn_mfma_f32_16x16x32_bf16(a0h, bh[ki], acc0, 0, 0, 0);
            acc1 = __builtin_amdgcn_mfma_f32_16x16x32_bf16(a1h, bh[ki], acc1, 0, 0, 0);
            acc0 = __builtin_amdgcn_mfma_f32_16x16x32_bf16(a0l, bh[ki], acc0, 0, 0, 0);
            acc1 = __builtin_amdgcn_mfma_f32_16x16x32_bf16(a1l, bh[ki], acc1, 0, 0, 0);
            acc0 = __builtin_amdgcn_mfma_f32_16x16x32_bf16(a0h, bl[ki], acc0, 0, 0, 0);
            acc1 = __builtin_amdgcn_mfma_f32_16x16x32_bf16(a1h, bl[ki], acc1, 0, 0, 0);
        }
        if (t + 1 < T && tid < 32) {
            const float* p = a.data + (size_t)(m0 + tid) * (5 * (T + 1)) + (size_t)(t + 1) * 5;
#pragma unroll
            for (int j = 0; j < 5; j++) smx[(t + 1) & 1][tid * 5 + j] = p[j];
        }
        unsigned short* __restrict__ hnh = a.hs_hi + (size_t)(t + 1) * B * D;
        unsigned short* __restrict__ hnl = a.hlo_pp + (size_t)po * B * D;
        const float* xb = smx[t & 1];
#pragma unroll
        for (int mi = 0; mi < 2; mi++) {
            f32x4 acc = mi ? acc1 : acc0;
#pragma unroll
            for (int rr = 0; rr < 4; rr++) {
                int brow = mi * 16 + q * 4 + rr;
                float v = acc[rr] + zgc[mi][rr] + xb[brow * 5 + 0] * wx0 + xb[brow * 5 + 1] * wx1 +
                          xb[brow * 5 + 2] * wx2 + xb[brow * 5 + 3] * wx3 + xb[brow * 5 + 4] * wx4;
                float hnew = lstm_quad(v, g, creg[mi][rr]);
                store_h_pair(hnew, r, hnh, hnl, (size_t)(m0 + brow) * D + d_even);
            }
        }
        group_barrier(ctr, 32u * (unsigned)(t + 1));
    }
}

DEVI void run_encout(const CoopArgs& a, float* smem) {
    int b = blockIdx.x, tid = threadIdx.x;
    if (tid < 128) {
        smem[tid]       = bf2f(a.hf_hi[(size_t)b * H + tid])       + bf2f(a.hf_lo[(size_t)b * H + tid]);
        smem[tid + 128] = bf2f(a.hf_hi[(size_t)b * H + tid + 128]) + bf2f(a.hf_lo[(size_t)b * H + tid + 128]);
        smem[tid + 256] = bf2f(a.hb_hi[(size_t)b * H + tid])       + bf2f(a.hb_lo[(size_t)b * H + tid]);
        smem[tid + 384] = bf2f(a.hb_hi[(size_t)b * H + tid + 128]) + bf2f(a.hb_lo[(size_t)b * H + tid + 128]);
    }
    __syncthreads();
    if (tid < 128) {
        float mean = a.eob[tid], lv = a.eob[Z + tid];
        for (int k = 0; k < 2 * H; k++) {
            float h = smem[k];
            mean += h * a.eoW[(size_t)k * 2 * Z + tid];
            lv += h * a.eoW[(size_t)k * 2 * Z + Z + tid];
        }
        float z = mean + __expf(0.5f * lv) * a.eps[(size_t)b * Z + tid];
        a.out[OUT_ZM + (size_t)b * Z + tid] = mean;
        a.out[OUT_ZL + (size_t)b * Z + tid] = lv;
        a.zbuf[(size_t)b * Z + tid] = z;
    }
    __syncthreads();
}

DEVI void run_init_zg(const CoopArgs& a, float* smem) {
    int bid = blockIdx.x, tid = threadIdx.x;
    if (bid < 64) {
        int cc = (bid & 3) * 256 + tid;
        int b0 = (bid >> 2) * 16;
        for (int i = tid; i < 16 * Z; i += 256)
            smem[i] = a.zbuf[(size_t)(b0 + (i >> 7)) * Z + (i & 127)];
        __syncthreads();
        float acc[16];
        float bias = a.ib[cc];
#pragma unroll
        for (int bb = 0; bb < 16; bb++) acc[bb] = bias;
        for (int k = 0; k < Z; k++) {
            float wv = a.iW[(size_t)k * 1024 + cc];
#pragma unroll
            for (int bb = 0; bb < 16; bb++) acc[bb] += smem[bb * 128 + k] * wv;
        }
        for (int bb = 0; bb < 16; bb++) {
            float v = tanh_(acc[bb]);
            int b = b0 + bb;
            if (cc < D) {
                unsigned short hi = f2bf(v);
                a.hs_hi[(size_t)b * D + cc] = hi;
                a.hlo_pp[(size_t)b * D + cc] = f2bf(v - bf2f(hi));
            } else {
                a.c32_d[(size_t)b * D + (cc - D)] = v;
            }
        }
    } else if (bid < 192) {
        int bid2 = bid - 64;
        int cc = (bid2 & 7) * 256 + tid;
        int b0 = (bid2 >> 3) * 16;
        for (int i = tid; i < 16 * Z; i += 256)
            smem[i] = a.zbuf[(size_t)(b0 + (i >> 7)) * Z + (i & 127)];
        __syncthreads();
        float acc[16];
        float db_c = a.db[cc];
#pragma unroll
        for (int bb = 0; bb < 16; bb++) acc[bb] = db_c;
        for (int k = 0; k < Z; k++) {
            float wv = a.dWx[(size_t)(5 + k) * 2048 + cc];
#pragma unroll
            for (int bb = 0; bb < 16; bb++) acc[bb] += smem[bb * 128 + k] * wv;
        }
        int n = 4 * (cc & 511) + (cc >> 9);
#pragma unroll
        for (int bb = 0; bb < 16; bb++) a.zg[(size_t)(b0 + bb) * 2048 + n] = acc[bb];
    }
    __syncthreads();
}

__global__ __launch_bounds__(256, 1) void k_coop(CoopArgs a) {
    __shared__ float smem[2048];
    __shared__ float smx[2][160];
    run_encoder(a, smx);
    cg::this_grid().sync();
    run_encout(a, smem);
    cg::this_grid().sync();
    run_init_zg(a, smem);
    cg::this_grid().sync();
    run_decoder(a, smx);
}

// ---------------- mix GEMM ----------------
__global__ __launch_bounds__(256) void k_mix(const unsigned short* __restrict__ hs,
                                             const unsigned short* __restrict__ mixwt,
                                             const float* __restrict__ mb, float* __restrict__ dout) {
    int tid = threadIdx.x, wave = tid >> 6, lane = tid & 63, q = lane >> 4, r = lane & 15;
    int m0 = blockIdx.y * 64 + (wave >> 1) * 32;
    int n0 = blockIdx.x * 64 + (wave & 1) * 32;
    const unsigned short* A = hs + (size_t)B * D;
    f32x4 acc[2][2];
#pragma unroll
    for (int mi = 0; mi < 2; mi++)
#pragma unroll
        for (int ni = 0; ni < 2; ni++) acc[mi][ni] = {0.f, 0.f, 0.f, 0.f};
#pragma unroll 4
    for (int kk = 0; kk < D; kk += 32) {
        int kb = kk + q * 8;
        short8 a0 = *(const short8*)(A + (size_t)(m0 + r) * D + kb);
        short8 a1 = *(const short8*)(A + (size_t)(m0 + 16 + r) * D + kb);
        short8 b0 = *(const short8*)(mixwt + (size_t)(n0 + r) * D + kb);
        short8 b1 = *(const short8*)(mixwt + (size_t)(n0 + 16 + r) * D + kb);
        acc[0][0] = __builtin_amdgcn_mfma_f32_16x16x32_bf16(a0, b0, acc[0][0], 0, 0, 0);
        acc[0][1] = __builtin_amdgcn_mfma_f32_16x16x32_bf16(a0, b1, acc[0][1], 0, 0, 0);
        acc[1][0] = __builtin_amdgcn_mfma_f32_16x16x32_bf16(a1, b0, acc[1][0], 0, 0, 0);
        acc[1][1] = __builtin_amdgcn_mfma_f32_16x16x32_bf16(a1, b1, acc[1][1], 0, 0, 0);
    }
#pragma unroll
    for (int ni = 0; ni < 2; ni++) {
        int ncol = n0 + ni * 16 + r;
        if (ncol < P) {
            float bias = mb[ncol];
#pragma unroll
            for (int mi = 0; mi < 2; mi++) {
#pragma unroll
                for (int rr = 0; rr < 4; rr++) {
                    int m = m0 + mi * 16 + q * 4 + rr;
                    int b = m & 255, t = m >> 8;
                    dout[((size_t)b * T + t) * P + ncol] = acc[mi][ni][rr] + bias;
                }
            }
        }
    }
}

// ---------------- per-row epilogue ----------------
__global__ void k_post(float* __restrict__ dout) {
    __shared__ float row[P];
    int rid = blockIdx.x;
    int tid = threadIdx.x;
    float* base = dout + (size_t)rid * P;
    float v = 0.f;
    if (tid < P) { v = base[tid]; row[tid] = v; }
    __syncthreads();
    if (tid < P) {
        float o;
        if (tid < KMIX) {
            float mx = row[0];
            for (int i = 1; i < KMIX; i++) mx = fmaxf(mx, row[i]);
            float sm = 0.f;
            for (int i = 0; i < KMIX; i++) sm += __expf(row[i] - mx);
            o = __expf(v - mx) / sm;
        } else if (tid < 3 * KMIX) o = v;
        else if (tid < 5 * KMIX) o = __expf(v);
        else if (tid < 6 * KMIX) o = tanh_(v);
        else o = v;
        base[tid] = o;
    }
}

extern "C" void kernel_launch(void* const* d_in, const int* in_sizes, int n_in,
                              void* d_out, int out_size, void* d_ws, size_t ws_size,
                              hipStream_t stream) {
    const float* data = (const float*)d_in[0];
    const float* eps  = (const float*)d_in[1];
    const float* eWxf = (const float*)d_in[2];
    const float* eWhf = (const float*)d_in[3];
    const float* ebf  = (const float*)d_in[4];
    const float* eWxb = (const float*)d_in[5];
    const float* eWhb = (const float*)d_in[6];
    const float* ebb  = (const float*)d_in[7];
    const float* eoW  = (const float*)d_in[8];
    const float* eob  = (const float*)d_in[9];
    const float* iW   = (const float*)d_in[10];
    const float* ib   = (const float*)d_in[11];
    const float* dWx  = (const float*)d_in[12];
    const float* dWh  = (const float*)d_in[13];
    const float* db   = (const float*)d_in[14];
    const float* mW   = (const float*)d_in[15];
    const float* mb   = (const float*)d_in[16];
    float* out = (float*)d_out;

    char* base = (char*)d_ws;
    size_t off = 0;
    auto alloc = [&](size_t bytes) -> char* {
        off = (off + 255) & ~(size_t)255;
        char* p = base + off;
        off += bytes;
        return p;
    };
    unsigned short* whd_hi = (unsigned short*)alloc((size_t)2048 * 512 * 2);
    unsigned short* whd_lo = (unsigned short*)alloc((size_t)2048 * 512 * 2);
    unsigned short* whf_hi = (unsigned short*)alloc((size_t)1024 * 256 * 2);
    unsigned short* whf_lo = (unsigned short*)alloc((size_t)1024 * 256 * 2);
    unsigned short* whb_hi = (unsigned short*)alloc((size_t)1024 * 256 * 2);
    unsigned short* whb_lo = (unsigned short*)alloc((size_t)1024 * 256 * 2);
    unsigned short* mixwt  = (unsigned short*)alloc((size_t)128 * 512 * 2);
    float* wxp_dec = (float*)alloc((size_t)5 * 2048 * 4);
    float* wxp_ef  = (float*)alloc((size_t)5 * 1024 * 4);
    float* wxp_eb  = (float*)alloc((size_t)5 * 1024 * 4);
    float* bp_ef   = (float*)alloc((size_t)1024 * 4);
    float* bp_eb   = (float*)alloc((size_t)1024 * 4);
    unsigned short* hf_hi = (unsigned short*)alloc((size_t)2 * B * H * 2);
    unsigned short* hf_lo = (unsigned short*)alloc((size_t)2 * B * H * 2);
    unsigned short* hb_hi = (unsigned short*)alloc((size_t)2 * B * H * 2);
    unsigned short* hb_lo = (unsigned short*)alloc((size_t)2 * B * H * 2);
    float* c32_d  = (float*)alloc((size_t)B * D * 4);
    unsigned short* hs_hi = (unsigned short*)alloc((size_t)(T + 1) * B * D * 2);
    unsigned short* hlo_pp = (unsigned short*)alloc((size_t)2 * B * D * 2);
    float* zbuf = (float*)alloc((size_t)B * Z * 4);
    float* zg   = (float*)alloc((size_t)B * 2048 * 4);
    unsigned* ctrs = (unsigned*)alloc(64 * 4);
    (void)ws_size; (void)in_sizes; (void)n_in; (void)out_size;

    k_zero<<<256, 256, 0, stream>>>(hf_hi, hb_hi, hf_lo, hb_lo, ctrs);
    k_pack_whT<512><<<dim3(64, 16), dim3(32, 8), 0, stream>>>(dWh, whd_hi, whd_lo);
    k_pack_whT<256><<<dim3(32, 8), dim3(32, 8), 0, stream>>>(eWhf, whf_hi, whf_lo);
    k_pack_whT<256><<<dim3(32, 8), dim3(32, 8), 0, stream>>>(eWhb, whb_hi, whb_lo);
    k_pack_mix<<<256, 256, 0, stream>>>(mW, mixwt);
    k_pack_cols<<<40, 256, 0, stream>>>(dWx, wxp_dec, 512, 2048);
    k_pack_cols<<<20, 256, 0, stream>>>(eWxf, wxp_ef, 256, 1024);
    k_pack_cols<<<20, 256, 0, stream>>>(eWxb, wxp_eb, 256, 1024);
    k_pack_cols<<<4, 256, 0, stream>>>(ebf, bp_ef, 256, 1024);
    k_pack_cols<<<4, 256, 0, stream>>>(ebb, bp_eb, 256, 1024);

    CoopArgs ca;
    ca.data = data; ca.eps = eps;
    ca.whf_hi = whf_hi; ca.whf_lo = whf_lo; ca.whb_hi = whb_hi; ca.whb_lo = whb_lo;
    ca.whd_hi = whd_hi; ca.whd_lo = whd_lo;
    ca.wxp_ef = wxp_ef; ca.wxp_eb = wxp_eb; ca.wxp_dec = wxp_dec;
    ca.bp_ef = bp_ef; ca.bp_eb = bp_eb;
    ca.eoW = eoW; ca.eob = eob; ca.iW = iW; ca.ib = ib; ca.dWx = dWx; ca.db = db;
    ca.hf_hi = hf_hi; ca.hf_lo = hf_lo; ca.hb_hi = hb_hi; ca.hb_lo = hb_lo;
    ca.c32_d = c32_d;
    ca.hs_hi = hs_hi; ca.hlo_pp = hlo_pp;
    ca.zbuf = zbuf; ca.zg = zg; ca.out = out; ca.ctrs = ctrs;

    void* kp[] = { &ca };
    hipLaunchCooperativeKernel((void*)k_coop, dim3(256), dim3(256), kp, 0, stream);

    k_mix<<<dim3(2, 1000), 256, 0, stream>>>(hs_hi, mixwt, mb, out);
    k_post<<<64000, 128, 0, stream>>>(out);
}

// Round 7
// 8517.759 us; speedup vs baseline: 2.3055x; 1.2473x over previous
//
#include <hip/hip_runtime.h>
#include <hip/hip_cooperative_groups.h>

namespace cg = cooperative_groups;

typedef __attribute__((ext_vector_type(8))) short short8;
typedef __attribute__((ext_vector_type(4))) float f32x4;

static constexpr int B = 256, T = 250, Z = 128, H = 256, D = 512, KMIX = 20, P = 123;
static constexpr int PARAMS_N = B * T * P;
static constexpr int OUT_ZM = PARAMS_N;
static constexpr int OUT_ZL = PARAMS_N + B * Z;

#define DEVI static __device__ __forceinline__

DEVI unsigned short f2bf(float f) {
    unsigned int u = __float_as_uint(f);
    u += 0x7fffu + ((u >> 16) & 1u);
    return (unsigned short)(u >> 16);
}
DEVI float bf2f(unsigned short s) { return __uint_as_float(((unsigned int)s) << 16); }
DEVI float sigm(float x) { return 1.0f / (1.0f + __expf(-x)); }
DEVI float tanh_(float x) {
    x = fminf(fmaxf(x, -15.0f), 15.0f);
    float e = __expf(2.0f * x);
    return (e - 1.0f) / (e + 1.0f);
}

// ---------------- zero-init (ws is poisoned 0xAA every replay) ----------------
__global__ void k_zero(unsigned short* h1, unsigned short* h2,
                       unsigned short* h1l, unsigned short* h2l, unsigned* ctrs) {
    int i = blockIdx.x * 256 + threadIdx.x;  // 65536 = B*H (slot 0 of each ping-pong)
    h1[i] = 0; h2[i] = 0; h1l[i] = 0; h2l[i] = 0;
    if (blockIdx.x == 0 && threadIdx.x < 64) ctrs[threadIdx.x] = 0;
}

// ---------------- weight packing ----------------
// Wh [K=HID][4*HID] fp32 -> hi/lo [4*HID][HID] bf16, rows packed n = 4*d + g
template <int HID>
__global__ void k_pack_whT(const float* __restrict__ Wh, unsigned short* __restrict__ ohi,
                           unsigned short* __restrict__ olo) {
    constexpr int N4 = 4 * HID;
    __shared__ float tile[32][33];
    int c0 = blockIdx.x * 32, k0 = blockIdx.y * 32;
    int tx = threadIdx.x, ty = threadIdx.y;
#pragma unroll
    for (int ii = 0; ii < 4; ii++)
        tile[ty + 8 * ii][tx] = Wh[(size_t)(k0 + ty + 8 * ii) * N4 + c0 + tx];
    __syncthreads();
#pragma unroll
    for (int ii = 0; ii < 4; ii++) {
        int j = ty + 8 * ii;
        int c = c0 + j;
        int g = c / HID, d = c % HID;
        float w = tile[tx][j];
        unsigned short hi = f2bf(w);
        unsigned short lo = f2bf(w - bf2f(hi));
        size_t o = (size_t)(4 * d + g) * HID + k0 + tx;
        ohi[o] = hi;
        olo[o] = lo;
    }
}

// mix_W [512][123] fp32 -> [128][512] bf16 (zero padded cols >=123)
__global__ void k_pack_mix(const float* __restrict__ W, unsigned short* __restrict__ out) {
    int idx = blockIdx.x * 256 + threadIdx.x;  // 128*512
    int n = idx >> 9, k = idx & 511;
    out[idx] = (n < P) ? f2bf(W[(size_t)k * P + n]) : (unsigned short)0;
}

// fp32 column permutation into packed gate order
__global__ void k_pack_cols(const float* __restrict__ in, float* __restrict__ out, int HID, int N4) {
    int idx = blockIdx.x * 256 + threadIdx.x;
    int row = idx / N4, n = idx % N4;
    out[idx] = in[(size_t)row * N4 + (n & 3) * HID + (n >> 2)];
}

// ---------------- cooperative persistent kernel ----------------
struct CoopArgs {
    const float* data;
    const float* eps;
    const unsigned short *whf_hi, *whf_lo, *whb_hi, *whb_lo, *whd_hi, *whd_lo;
    const float *wxp_ef, *wxp_eb, *wxp_dec, *bp_ef, *bp_eb;
    const float *eoW, *eob, *iW, *ib, *dWx, *db;
    unsigned short *hf_hi, *hf_lo, *hb_hi, *hb_lo;  // [2][B][H] ping-pong
    float* c32_d;
    unsigned short* hs_hi;   // [T+1][B][D] ring
    unsigned short* hlo_pp;  // [2][B][D] ping-pong
    float *zbuf, *zg;
    float* out;
    unsigned* ctrs;
};

// Group barrier. h-stores are agent-scope write-through atomics (sc1 -> MALL, L2
// never dirty), so a RELAXED add suffices for the signal (stores drained by the
// compiler's vmcnt(0) at the preceding __syncthreads). The ACQUIRE fence after the
// poll emits the buffer_inv that keeps plain cached reads (incl. L2-prefetched
// lines of the h ring/ping-pong) fresh. No wbl2 anywhere (nothing dirty).
DEVI void group_barrier(unsigned* ctr, unsigned target) {
    __syncthreads();
    if (threadIdx.x == 0) {
        __hip_atomic_fetch_add(ctr, 1u, __ATOMIC_RELAXED, __HIP_MEMORY_SCOPE_AGENT);
        while (__hip_atomic_load(ctr, __ATOMIC_RELAXED, __HIP_MEMORY_SCOPE_AGENT) < target)
            __builtin_amdgcn_s_sleep(2);
        __builtin_amdgcn_fence(__ATOMIC_ACQUIRE, "agent");
    }
    __syncthreads();
}

// quad-shuffle gate gather + pointwise update; c lives in a register (quad-redundant)
DEVI float lstm_quad(float v, int g, float& c) {
    float s1 = __shfl_xor(v, 1, 64);
    float s2 = __shfl_xor(v, 2, 64);
    float s3 = __shfl_xor(v, 3, 64);
    float gi, gf, gg, go;
    if (g == 0)      { gi = v;  gf = s1; gg = s2; go = s3; }
    else if (g == 1) { gi = s1; gf = v;  gg = s3; go = s2; }
    else if (g == 2) { gi = s2; gf = s3; gg = v;  go = s1; }
    else             { gi = s3; gf = s2; gg = s1; go = v;  }
    float cnew = sigm(gf) * c + sigm(gi) * tanh_(gg);
    c = cnew;
    return sigm(go) * tanh_(cnew);
}

// packed 4B agent-scope write-through stores of (hi_d, hi_{d+1}) and (lo_d, lo_{d+1})
DEVI void store_h_pair(float hnew, int r, unsigned short* __restrict__ hnh,
                       unsigned short* __restrict__ hnl, size_t o_even) {
    unsigned short hi = f2bf(hnew);
    float lo = hnew - bf2f(hi);
    float hp = __shfl_xor(hnew, 4, 64);   // partner lane: d ^ 1, same gate
    unsigned short hip = f2bf(hp);
    float lop = hp - bf2f(hip);
    if ((r & 7) == 0) {
        unsigned pk = (unsigned)hi | ((unsigned)hip << 16);
        __hip_atomic_store((unsigned*)(hnh + o_even), pk, __ATOMIC_RELAXED, __HIP_MEMORY_SCOPE_AGENT);
    } else if ((r & 7) == 1) {
        unsigned pk = (unsigned)f2bf(lo) | ((unsigned)f2bf(lop) << 16);
        __hip_atomic_store((unsigned*)(hnl + o_even), pk, __ATOMIC_RELAXED, __HIP_MEMORY_SCOPE_AGENT);
    }
}

DEVI void run_encoder(const CoopArgs& a, float (*smx)[160]) {
    int bid = blockIdx.x;
    int dir = bid >> 7, mb = (bid >> 4) & 7, nb = bid & 15;
    int tid = threadIdx.x, w = tid >> 6, lane = tid & 63, q = lane >> 4, r = lane & 15;
    int m0 = mb * 32;
    const unsigned short* __restrict__ whi = dir ? a.whb_hi : a.whf_hi;
    const unsigned short* __restrict__ wlo = dir ? a.whb_lo : a.whf_lo;
    const float* __restrict__ wxp = dir ? a.wxp_eb : a.wxp_ef;
    const float* __restrict__ bp = dir ? a.bp_eb : a.bp_ef;
    unsigned short* __restrict__ hhi = dir ? a.hb_hi : a.hf_hi;
    unsigned short* __restrict__ hlo = dir ? a.hb_lo : a.hf_lo;
    unsigned* ctr = a.ctrs + dir * 8 + mb;

    int c = nb * 64 + w * 16 + r;
    int g = r & 3, d = c >> 2;
    size_t d_even = (size_t)(d & ~1);

    short8 bh[8], bl[8];
#pragma unroll
    for (int ki = 0; ki < 8; ki++) {
        bh[ki] = *(const short8*)(whi + (size_t)c * H + ki * 32 + q * 8);
        bl[ki] = *(const short8*)(wlo + (size_t)c * H + ki * 32 + q * 8);
    }
    float wx0 = wxp[0 * 1024 + c], wx1 = wxp[1 * 1024 + c], wx2 = wxp[2 * 1024 + c];
    float wx3 = wxp[3 * 1024 + c], wx4 = wxp[4 * 1024 + c];
    float bias = bp[c];
    float creg[2][4];
#pragma unroll
    for (int mi = 0; mi < 2; mi++)
#pragma unroll
        for (int rr = 0; rr < 4; rr++) creg[mi][rr] = 0.f;

    // stage x(t=0) into LDS buf 0
    {
        int tt0 = dir ? 250 : 1;
        if (tid < 32) {
            const float* p = a.data + (size_t)(m0 + tid) * (5 * (T + 1)) + (size_t)tt0 * 5;
#pragma unroll
            for (int j = 0; j < 5; j++) smx[0][tid * 5 + j] = p[j];
        }
    }
    __syncthreads();

    for (int t = 0; t < T; t++) {
        int pi = t & 1;
        const unsigned short* __restrict__ hph = hhi + (size_t)pi * B * H;
        const unsigned short* __restrict__ hpl = hlo + (size_t)pi * B * H;
        f32x4 acc0 = {0.f, 0.f, 0.f, 0.f}, acc1 = {0.f, 0.f, 0.f, 0.f};
#pragma unroll
        for (int ki = 0; ki < 8; ki++) {
            int kb = ki * 32 + q * 8;
            short8 a0h = *(const short8*)(hph + (size_t)(m0 + r) * H + kb);
            short8 a1h = *(const short8*)(hph + (size_t)(m0 + 16 + r) * H + kb);
            short8 a0l = *(const short8*)(hpl + (size_t)(m0 + r) * H + kb);
            short8 a1l = *(const short8*)(hpl + (size_t)(m0 + 16 + r) * H + kb);
            acc0 = __builtin_amdgcn_mfma_f32_16x16x32_bf16(a0h, bh[ki], acc0, 0, 0, 0);
            acc1 = __builtin_amdgcn_mfma_f32_16x16x32_bf16(a1h, bh[ki], acc1, 0, 0, 0);
            acc0 = __builtin_amdgcn_mfma_f32_16x16x32_bf16(a0l, bh[ki], acc0, 0, 0, 0);
            acc1 = __builtin_amdgcn_mfma_f32_16x16x32_bf16(a1l, bh[ki], acc1, 0, 0, 0);
            acc0 = __builtin_amdgcn_mfma_f32_16x16x32_bf16(a0h, bl[ki], acc0, 0, 0, 0);
            acc1 = __builtin_amdgcn_mfma_f32_16x16x32_bf16(a1h, bl[ki], acc1, 0, 0, 0);
        }
        // prefetch x(t+1) into the other LDS buffer (overlaps epilogue)
        if (t + 1 < T && tid < 32) {
            int ttn = dir ? (249 - t) : (2 + t);
            const float* p = a.data + (size_t)(m0 + tid) * (5 * (T + 1)) + (size_t)ttn * 5;
#pragma unroll
            for (int j = 0; j < 5; j++) smx[(t + 1) & 1][tid * 5 + j] = p[j];
        }
        unsigned short* __restrict__ hnh = hhi + (size_t)(1 - pi) * B * H;
        unsigned short* __restrict__ hnl = hlo + (size_t)(1 - pi) * B * H;
        const float* xb = smx[t & 1];
#pragma unroll
        for (int mi = 0; mi < 2; mi++) {
            f32x4 acc = mi ? acc1 : acc0;
#pragma unroll
            for (int rr = 0; rr < 4; rr++) {
                int brow = mi * 16 + q * 4 + rr;
                float v = acc[rr] + bias + xb[brow * 5 + 0] * wx0 + xb[brow * 5 + 1] * wx1 +
                          xb[brow * 5 + 2] * wx2 + xb[brow * 5 + 3] * wx3 + xb[brow * 5 + 4] * wx4;
                float hnew = lstm_quad(v, g, creg[mi][rr]);
                store_h_pair(hnew, r, hnh, hnl, (size_t)(m0 + brow) * H + d_even);
            }
        }
        group_barrier(ctr, 16u * (unsigned)(t + 1));
    }
}

DEVI void run_decoder(const CoopArgs& a, float (*smx)[160]) {
    int bid = blockIdx.x;
    int mb = bid >> 5, nb = bid & 31;
    int tid = threadIdx.x, w = tid >> 6, lane = tid & 63, q = lane >> 4, r = lane & 15;
    int m0 = mb * 32;
    unsigned* ctr = a.ctrs + 16 + mb;

    int c = nb * 64 + w * 16 + r;
    int g = r & 3, d = c >> 2;
    size_t d_even = (size_t)(d & ~1);

    short8 bh[16], bl[16];
#pragma unroll
    for (int ki = 0; ki < 16; ki++) {
        bh[ki] = *(const short8*)(a.whd_hi + (size_t)c * D + ki * 32 + q * 8);
        bl[ki] = *(const short8*)(a.whd_lo + (size_t)c * D + ki * 32 + q * 8);
    }
    float wx0 = a.wxp_dec[0 * 2048 + c], wx1 = a.wxp_dec[1 * 2048 + c], wx2 = a.wxp_dec[2 * 2048 + c];
    float wx3 = a.wxp_dec[3 * 2048 + c], wx4 = a.wxp_dec[4 * 2048 + c];
    float zgc[2][4], creg[2][4];
#pragma unroll
    for (int mi = 0; mi < 2; mi++)
#pragma unroll
        for (int rr = 0; rr < 4; rr++) {
            int b = m0 + mi * 16 + q * 4 + rr;
            zgc[mi][rr] = a.zg[(size_t)b * 2048 + c];
            creg[mi][rr] = a.c32_d[(size_t)b * D + d];
        }

    if (tid < 32) {
        const float* p = a.data + (size_t)(m0 + tid) * (5 * (T + 1));
#pragma unroll
        for (int j = 0; j < 5; j++) smx[0][tid * 5 + j] = p[j];
    }
    __syncthreads();

    for (int t = 0; t < T; t++) {
        int pi = t & 1;
        const unsigned short* __restrict__ hph = a.hs_hi + (size_t)t * B * D;
        const unsigned short* __restrict__ hpl = a.hlo_pp + (size_t)pi * B * D;
        f32x4 acc0 = {0.f, 0.f, 0.f, 0.f}, acc1 = {0.f, 0.f, 0.f, 0.f};
#pragma unroll
        for (int ki = 0; ki < 16; ki++) {
            int kb = ki * 32 + q * 8;
            short8 a0h = *(const short8*)(hph + (size_t)(m0 + r) * D + kb);
            short8 a1h = *(const short8*)(hph + (size_t)(m0 + 16 + r) * D + kb);
            short8 a0l = *(const short8*)(hpl + (size_t)(m0 + r) * D + kb);
            short8 a1l = *(const short8*)(hpl + (size_t)(m0 + 16 + r) * D + kb);
            acc0 = __builtin_amdgcn_mfma_f32_16x16x32_bf16(a0h, bh[ki], acc0, 0, 0, 0);
            acc1 = __builtin_amdgcn_mfma_f32_16x16x32_bf16(a1h, bh[ki], acc1, 0, 0, 0);
            acc0 = __builtin_amdgcn_mfma_f32_16x16x32_bf16(a0l, bh[ki], acc0, 0, 0, 0);
            acc1 = __builtin_amdgcn_mfma_f32_16x16x32_bf16(a1l, bh[ki], acc1, 0, 0, 0);
            acc0 = __builtin_amdgcn_mfma_f32_16x16x32_bf16(a0h, bl[ki], acc0, 0, 0, 0);
            acc1 = __builtin_amdgcn_mfma_f32_16x16x32_bf16(a1h, bl[ki], acc1, 0, 0, 0);
        }
        if (t + 1 < T && tid < 32) {
            const float* p = a.data + (size_t)(m0 + tid) * (5 * (T + 1)) + (size_t)(t + 1) * 5;
#pragma unroll
            for (int j = 0; j < 5; j++) smx[(t + 1) & 1][tid * 5 + j] = p[j];
        }
        unsigned short* __restrict__ hnh = a.hs_hi + (size_t)(t + 1) * B * D;
        unsigned short* __restrict__ hnl = a.hlo_pp + (size_t)(1 - pi) * B * D;
        const float* xb = smx[t & 1];
#pragma unroll
        for (int mi = 0; mi < 2; mi++) {
            f32x4 acc = mi ? acc1 : acc0;
#pragma unroll
            for (int rr = 0; rr < 4; rr++) {
                int brow = mi * 16 + q * 4 + rr;
                float v = acc[rr] + zgc[mi][rr] + xb[brow * 5 + 0] * wx0 + xb[brow * 5 + 1] * wx1 +
                          xb[brow * 5 + 2] * wx2 + xb[brow * 5 + 3] * wx3 + xb[brow * 5 + 4] * wx4;
                float hnew = lstm_quad(v, g, creg[mi][rr]);
                store_h_pair(hnew, r, hnh, hnl, (size_t)(m0 + brow) * D + d_even);
            }
        }
        group_barrier(ctr, 32u * (unsigned)(t + 1));
    }
}

DEVI void run_encout(const CoopArgs& a, float* smem) {
    int b = blockIdx.x, tid = threadIdx.x;
    // final encoder h is in ping-pong slot 0 (T=250 even)
    if (tid < 128) {
        smem[tid]       = bf2f(a.hf_hi[(size_t)b * H + tid])       + bf2f(a.hf_lo[(size_t)b * H + tid]);
        smem[tid + 128] = bf2f(a.hf_hi[(size_t)b * H + tid + 128]) + bf2f(a.hf_lo[(size_t)b * H + tid + 128]);
        smem[tid + 256] = bf2f(a.hb_hi[(size_t)b * H + tid])       + bf2f(a.hb_lo[(size_t)b * H + tid]);
        smem[tid + 384] = bf2f(a.hb_hi[(size_t)b * H + tid + 128]) + bf2f(a.hb_lo[(size_t)b * H + tid + 128]);
    }
    __syncthreads();
    if (tid < 128) {
        float mean = a.eob[tid], lv = a.eob[Z + tid];
        for (int k = 0; k < 2 * H; k++) {
            float h = smem[k];
            mean += h * a.eoW[(size_t)k * 2 * Z + tid];
            lv += h * a.eoW[(size_t)k * 2 * Z + Z + tid];
        }
        float z = mean + __expf(0.5f * lv) * a.eps[(size_t)b * Z + tid];
        a.out[OUT_ZM + (size_t)b * Z + tid] = mean;
        a.out[OUT_ZL + (size_t)b * Z + tid] = lv;
        a.zbuf[(size_t)b * Z + tid] = z;
    }
    __syncthreads();
}

DEVI void run_init_zg(const CoopArgs& a, float* smem) {
    int bid = blockIdx.x, tid = threadIdx.x;
    if (bid < 64) {
        int cc = (bid & 3) * 256 + tid;
        int b0 = (bid >> 2) * 16;
        for (int i = tid; i < 16 * Z; i += 256)
            smem[i] = a.zbuf[(size_t)(b0 + (i >> 7)) * Z + (i & 127)];
        __syncthreads();
        float acc[16];
        float bias = a.ib[cc];
#pragma unroll
        for (int bb = 0; bb < 16; bb++) acc[bb] = bias;
        for (int k = 0; k < Z; k++) {
            float wv = a.iW[(size_t)k * 1024 + cc];
#pragma unroll
            for (int bb = 0; bb < 16; bb++) acc[bb] += smem[bb * 128 + k] * wv;
        }
        for (int bb = 0; bb < 16; bb++) {
            float v = tanh_(acc[bb]);
            int b = b0 + bb;
            if (cc < D) {
                unsigned short hi = f2bf(v);
                a.hs_hi[(size_t)b * D + cc] = hi;
                a.hlo_pp[(size_t)b * D + cc] = f2bf(v - bf2f(hi));
            } else {
                a.c32_d[(size_t)b * D + (cc - D)] = v;
            }
        }
    } else if (bid < 192) {
        int bid2 = bid - 64;
        int cc = (bid2 & 7) * 256 + tid;
        int b0 = (bid2 >> 3) * 16;
        for (int i = tid; i < 16 * Z; i += 256)
            smem[i] = a.zbuf[(size_t)(b0 + (i >> 7)) * Z + (i & 127)];
        __syncthreads();
        float acc[16];
        float db_c = a.db[cc];
#pragma unroll
        for (int bb = 0; bb < 16; bb++) acc[bb] = db_c;
        for (int k = 0; k < Z; k++) {
            float wv = a.dWx[(size_t)(5 + k) * 2048 + cc];
#pragma unroll
            for (int bb = 0; bb < 16; bb++) acc[bb] += smem[bb * 128 + k] * wv;
        }
        int n = 4 * (cc & 511) + (cc >> 9);
#pragma unroll
        for (int bb = 0; bb < 16; bb++) a.zg[(size_t)(b0 + bb) * 2048 + n] = acc[bb];
    }
    __syncthreads();
}

__global__ __launch_bounds__(256, 1) void k_coop(CoopArgs a) {
    __shared__ float smem[2048];
    __shared__ float smx[2][160];
    run_encoder(a, smx);
    cg::this_grid().sync();
    run_encout(a, smem);
    cg::this_grid().sync();
    run_init_zg(a, smem);
    cg::this_grid().sync();
    run_decoder(a, smx);
}

// ---------------- mix GEMM ----------------
__global__ __launch_bounds__(256) void k_mix(const unsigned short* __restrict__ hs,
                                             const unsigned short* __restrict__ mixwt,
                                             const float* __restrict__ mb, float* __restrict__ dout) {
    int tid = threadIdx.x, wave = tid >> 6, lane = tid & 63, q = lane >> 4, r = lane & 15;
    int m0 = blockIdx.y * 64 + (wave >> 1) * 32;
    int n0 = blockIdx.x * 64 + (wave & 1) * 32;
    const unsigned short* A = hs + (size_t)B * D;  // ring slots 1..T
    f32x4 acc[2][2];
#pragma unroll
    for (int mi = 0; mi < 2; mi++)
#pragma unroll
        for (int ni = 0; ni < 2; ni++) acc[mi][ni] = {0.f, 0.f, 0.f, 0.f};
#pragma unroll 4
    for (int kk = 0; kk < D; kk += 32) {
        int kb = kk + q * 8;
        short8 a0 = *(const short8*)(A + (size_t)(m0 + r) * D + kb);
        short8 a1 = *(const short8*)(A + (size_t)(m0 + 16 + r) * D + kb);
        short8 b0 = *(const short8*)(mixwt + (size_t)(n0 + r) * D + kb);
        short8 b1 = *(const short8*)(mixwt + (size_t)(n0 + 16 + r) * D + kb);
        acc[0][0] = __builtin_amdgcn_mfma_f32_16x16x32_bf16(a0, b0, acc[0][0], 0, 0, 0);
        acc[0][1] = __builtin_amdgcn_mfma_f32_16x16x32_bf16(a0, b1, acc[0][1], 0, 0, 0);
        acc[1][0] = __builtin_amdgcn_mfma_f32_16x16x32_bf16(a1, b0, acc[1][0], 0, 0, 0);
        acc[1][1] = __builtin_amdgcn_mfma_f32_16x16x32_bf16(a1, b1, acc[1][1], 0, 0, 0);
    }
#pragma unroll
    for (int ni = 0; ni < 2; ni++) {
        int ncol = n0 + ni * 16 + r;
        if (ncol < P) {
            float bias = mb[ncol];
#pragma unroll
            for (int mi = 0; mi < 2; mi++) {
#pragma unroll
                for (int rr = 0; rr < 4; rr++) {
                    int m = m0 + mi * 16 + q * 4 + rr;
                    int b = m & 255, t = m >> 8;
                    dout[((size_t)b * T + t) * P + ncol] = acc[mi][ni][rr] + bias;
                }
            }
        }
    }
}

// ---------------- per-row epilogue ----------------
__global__ void k_post(float* __restrict__ dout) {
    __shared__ float row[P];
    int rid = blockIdx.x;
    int tid = threadIdx.x;
    float* base = dout + (size_t)rid * P;
    float v = 0.f;
    if (tid < P) { v = base[tid]; row[tid] = v; }
    __syncthreads();
    if (tid < P) {
        float o;
        if (tid < KMIX) {
            float mx = row[0];
            for (int i = 1; i < KMIX; i++) mx = fmaxf(mx, row[i]);
            float sm = 0.f;
            for (int i = 0; i < KMIX; i++) sm += __expf(row[i] - mx);
            o = __expf(v - mx) / sm;
        } else if (tid < 3 * KMIX) o = v;
        else if (tid < 5 * KMIX) o = __expf(v);
        else if (tid < 6 * KMIX) o = tanh_(v);
        else o = v;
        base[tid] = o;
    }
}

extern "C" void kernel_launch(void* const* d_in, const int* in_sizes, int n_in,
                              void* d_out, int out_size, void* d_ws, size_t ws_size,
                              hipStream_t stream) {
    const float* data = (const float*)d_in[0];
    const float* eps  = (const float*)d_in[1];
    const float* eWxf = (const float*)d_in[2];
    const float* eWhf = (const float*)d_in[3];
    const float* ebf  = (const float*)d_in[4];
    const float* eWxb = (const float*)d_in[5];
    const float* eWhb = (const float*)d_in[6];
    const float* ebb  = (const float*)d_in[7];
    const float* eoW  = (const float*)d_in[8];
    const float* eob  = (const float*)d_in[9];
    const float* iW   = (const float*)d_in[10];
    const float* ib   = (const float*)d_in[11];
    const float* dWx  = (const float*)d_in[12];
    const float* dWh  = (const float*)d_in[13];
    const float* db   = (const float*)d_in[14];
    const float* mW   = (const float*)d_in[15];
    const float* mb   = (const float*)d_in[16];
    float* out = (float*)d_out;

    char* base = (char*)d_ws;
    size_t off = 0;
    auto alloc = [&](size_t bytes) -> char* {
        off = (off + 255) & ~(size_t)255;
        char* p = base + off;
        off += bytes;
        return p;
    };
    unsigned short* whd_hi = (unsigned short*)alloc((size_t)2048 * 512 * 2);
    unsigned short* whd_lo = (unsigned short*)alloc((size_t)2048 * 512 * 2);
    unsigned short* whf_hi = (unsigned short*)alloc((size_t)1024 * 256 * 2);
    unsigned short* whf_lo = (unsigned short*)alloc((size_t)1024 * 256 * 2);
    unsigned short* whb_hi = (unsigned short*)alloc((size_t)1024 * 256 * 2);
    unsigned short* whb_lo = (unsigned short*)alloc((size_t)1024 * 256 * 2);
    unsigned short* mixwt  = (unsigned short*)alloc((size_t)128 * 512 * 2);
    float* wxp_dec = (float*)alloc((size_t)5 * 2048 * 4);
    float* wxp_ef  = (float*)alloc((size_t)5 * 1024 * 4);
    float* wxp_eb  = (float*)alloc((size_t)5 * 1024 * 4);
    float* bp_ef   = (float*)alloc((size_t)1024 * 4);
    float* bp_eb   = (float*)alloc((size_t)1024 * 4);
    unsigned short* hf_hi = (unsigned short*)alloc((size_t)2 * B * H * 2);
    unsigned short* hf_lo = (unsigned short*)alloc((size_t)2 * B * H * 2);
    unsigned short* hb_hi = (unsigned short*)alloc((size_t)2 * B * H * 2);
    unsigned short* hb_lo = (unsigned short*)alloc((size_t)2 * B * H * 2);
    float* c32_d  = (float*)alloc((size_t)B * D * 4);
    unsigned short* hs_hi = (unsigned short*)alloc((size_t)(T + 1) * B * D * 2);
    unsigned short* hlo_pp = (unsigned short*)alloc((size_t)2 * B * D * 2);
    float* zbuf = (float*)alloc((size_t)B * Z * 4);
    float* zg   = (float*)alloc((size_t)B * 2048 * 4);
    unsigned* ctrs = (unsigned*)alloc(64 * 4);
    (void)ws_size; (void)in_sizes; (void)n_in; (void)out_size;

    k_zero<<<256, 256, 0, stream>>>(hf_hi, hb_hi, hf_lo, hb_lo, ctrs);
    k_pack_whT<512><<<dim3(64, 16), dim3(32, 8), 0, stream>>>(dWh, whd_hi, whd_lo);
    k_pack_whT<256><<<dim3(32, 8), dim3(32, 8), 0, stream>>>(eWhf, whf_hi, whf_lo);
    k_pack_whT<256><<<dim3(32, 8), dim3(32, 8), 0, stream>>>(eWhb, whb_hi, whb_lo);
    k_pack_mix<<<256, 256, 0, stream>>>(mW, mixwt);
    k_pack_cols<<<40, 256, 0, stream>>>(dWx, wxp_dec, 512, 2048);
    k_pack_cols<<<20, 256, 0, stream>>>(eWxf, wxp_ef, 256, 1024);
    k_pack_cols<<<20, 256, 0, stream>>>(eWxb, wxp_eb, 256, 1024);
    k_pack_cols<<<4, 256, 0, stream>>>(ebf, bp_ef, 256, 1024);
    k_pack_cols<<<4, 256, 0, stream>>>(ebb, bp_eb, 256, 1024);

    CoopArgs ca;
    ca.data = data; ca.eps = eps;
    ca.whf_hi = whf_hi; ca.whf_lo = whf_lo; ca.whb_hi = whb_hi; ca.whb_lo = whb_lo;
    ca.whd_hi = whd_hi; ca.whd_lo = whd_lo;
    ca.wxp_ef = wxp_ef; ca.wxp_eb = wxp_eb; ca.wxp_dec = wxp_dec;
    ca.bp_ef = bp_ef; ca.bp_eb = bp_eb;
    ca.eoW = eoW; ca.eob = eob; ca.iW = iW; ca.ib = ib; ca.dWx = dWx; ca.db = db;
    ca.hf_hi = hf_hi; ca.hf_lo = hf_lo; ca.hb_hi = hb_hi; ca.hb_lo = hb_lo;
    ca.c32_d = c32_d;
    ca.hs_hi = hs_hi; ca.hlo_pp = hlo_pp;
    ca.zbuf = zbuf; ca.zg = zg; ca.out = out; ca.ctrs = ctrs;

    void* kp[] = { &ca };
    hipLaunchCooperativeKernel((void*)k_coop, dim3(256), dim3(256), kp, 0, stream);

    k_mix<<<dim3(2, 1000), 256, 0, stream>>>(hs_hi, mixwt, mb, out);
    k_post<<<64000, 128, 0, stream>>>(out);
}

// Round 9
// 5861.662 us; speedup vs baseline: 3.3502x; 1.4531x over previous
//
#include <hip/hip_runtime.h>
#include <hip/hip_cooperative_groups.h>

namespace cg = cooperative_groups;

typedef __attribute__((ext_vector_type(8))) short short8;
typedef __attribute__((ext_vector_type(4))) float f32x4;

static constexpr int B = 256, T = 250, Z = 128, H = 256, D = 512, KMIX = 20, P = 123;
static constexpr int PARAMS_N = B * T * P;
static constexpr int OUT_ZM = PARAMS_N;
static constexpr int OUT_ZL = PARAMS_N + B * Z;

#define DEVI static __device__ __forceinline__

DEVI unsigned short f2bf(float f) {
    unsigned int u = __float_as_uint(f);
    u += 0x7fffu + ((u >> 16) & 1u);
    return (unsigned short)(u >> 16);
}
DEVI float bf2f(unsigned short s) { return __uint_as_float(((unsigned int)s) << 16); }
DEVI float sigm(float x) { return 1.0f / (1.0f + __expf(-x)); }
DEVI float tanh_(float x) {
    x = fminf(fmaxf(x, -15.0f), 15.0f);
    float e = __expf(2.0f * x);
    return (e - 1.0f) / (e + 1.0f);
}

// ---------------- zero-init (ws is poisoned 0xAA every replay) ----------------
// zeroes slot 0 of the 4 encoder ping-pongs + barrier flags/go
__global__ void k_zero(unsigned short* h1, unsigned short* h2,
                       unsigned short* h1l, unsigned short* h2l,
                       unsigned* flags, unsigned* go) {
    int i = blockIdx.x * 256 + threadIdx.x;  // 65536 = B*H
    h1[i] = 0; h2[i] = 0; h1l[i] = 0; h2l[i] = 0;
    if (i < 24 * 1024) flags[i] = 0;  // 24 groups x 32 blocks x 32 uints (128B spacing)
    if (i < 24 * 32) go[i] = 0;       // 24 groups x 1 line
}

// ---------------- weight packing ----------------
// Wh [K=HID][4*HID] fp32 -> hi/lo [4*HID][HID] bf16, rows packed n = 4*d + g
template <int HID>
__global__ void k_pack_whT(const float* __restrict__ Wh, unsigned short* __restrict__ ohi,
                           unsigned short* __restrict__ olo) {
    constexpr int N4 = 4 * HID;
    __shared__ float tile[32][33];
    int c0 = blockIdx.x * 32, k0 = blockIdx.y * 32;
    int tx = threadIdx.x, ty = threadIdx.y;
#pragma unroll
    for (int ii = 0; ii < 4; ii++)
        tile[ty + 8 * ii][tx] = Wh[(size_t)(k0 + ty + 8 * ii) * N4 + c0 + tx];
    __syncthreads();
#pragma unroll
    for (int ii = 0; ii < 4; ii++) {
        int j = ty + 8 * ii;
        int c = c0 + j;
        int g = c / HID, d = c % HID;
        float w = tile[tx][j];
        unsigned short hi = f2bf(w);
        unsigned short lo = f2bf(w - bf2f(hi));
        size_t o = (size_t)(4 * d + g) * HID + k0 + tx;
        ohi[o] = hi;
        olo[o] = lo;
    }
}

// mix_W [512][123] fp32 -> [128][512] bf16 (zero padded cols >=123)
__global__ void k_pack_mix(const float* __restrict__ W, unsigned short* __restrict__ out) {
    int idx = blockIdx.x * 256 + threadIdx.x;  // 128*512
    int n = idx >> 9, k = idx & 511;
    out[idx] = (n < P) ? f2bf(W[(size_t)k * P + n]) : (unsigned short)0;
}

// fp32 column permutation into packed gate order
__global__ void k_pack_cols(const float* __restrict__ in, float* __restrict__ out, int HID, int N4) {
    int idx = blockIdx.x * 256 + threadIdx.x;
    int row = idx / N4, n = idx % N4;
    out[idx] = in[(size_t)row * N4 + (n & 3) * HID + (n >> 2)];
}

// ---------------- cooperative persistent kernel ----------------
struct CoopArgs {
    const float* data;
    const float* eps;
    const unsigned short *whf_hi, *whf_lo, *whb_hi, *whb_lo, *whd_hi, *whd_lo;
    const float *wxp_ef, *wxp_eb, *wxp_dec, *bp_ef, *bp_eb;
    const float *eoW, *eob, *iW, *ib, *dWx, *db;
    unsigned short *hf_hi, *hf_lo, *hb_hi, *hb_lo;  // [2][B][H] ping-pong
    float* c32_d;
    unsigned short* hs_hi;   // [T+1][B][D] ring
    unsigned short* hlo_pp;  // [2][B][D] ping-pong
    float *zbuf, *zg;
    float* out;
    unsigned* flags;  // [24 groups][32 blocks][32 uints] arrival stamps, 128B apart
    unsigned* go;     // [24 groups][32 uints] broadcast stamp, 128B apart
};

// Flag-broadcast group barrier (replaces serialized RMW counter; keeps r7's
// proven acquire-fence semantics). Arrival: one sc-store per block to its OWN
// line (no contention). Leader block's wave 0 gathers all member flags in one
// 64-lane load; lane 0 publishes the per-group "go" stamp. Members read-only
// poll "go" (no RMW serialization). Data visibility: sc1 write-through stores
// drained by vmcnt(0) at the entry __syncthreads; the ACQUIRE fence after the
// poll invalidates L1/L2 before the next step's plain h reads (r4/r7-proven).
DEVI void group_barrier(unsigned* flags, unsigned* go, int grp, int myblk, int nblk,
                        unsigned stamp) {
    __syncthreads();
    int tid = threadIdx.x;
    unsigned* gf = flags + (size_t)grp * 1024;
    if (tid == 0)
        __hip_atomic_store(gf + myblk * 32, stamp, __ATOMIC_RELAXED, __HIP_MEMORY_SCOPE_AGENT);
    if (myblk == 0 && tid < 64) {
        for (;;) {
            unsigned v = (tid < nblk)
                ? __hip_atomic_load(gf + tid * 32, __ATOMIC_RELAXED, __HIP_MEMORY_SCOPE_AGENT)
                : stamp;
            if (__all(v >= stamp)) break;
            __builtin_amdgcn_s_sleep(1);
        }
        if (tid == 0)
            __hip_atomic_store(go + grp * 32, stamp, __ATOMIC_RELAXED, __HIP_MEMORY_SCOPE_AGENT);
    }
    if (tid == 0) {
        while (__hip_atomic_load(go + grp * 32, __ATOMIC_RELAXED, __HIP_MEMORY_SCOPE_AGENT) < stamp)
            __builtin_amdgcn_s_sleep(1);
        __builtin_amdgcn_fence(__ATOMIC_ACQUIRE, "agent");
    }
    __syncthreads();
}

// quad-shuffle gate gather + pointwise update; c lives in a register (quad-redundant)
DEVI float lstm_quad(float v, int g, float& c) {
    float s1 = __shfl_xor(v, 1, 64);
    float s2 = __shfl_xor(v, 2, 64);
    float s3 = __shfl_xor(v, 3, 64);
    float gi, gf, gg, go;
    if (g == 0)      { gi = v;  gf = s1; gg = s2; go = s3; }
    else if (g == 1) { gi = s1; gf = v;  gg = s3; go = s2; }
    else if (g == 2) { gi = s2; gf = s3; gg = v;  go = s1; }
    else             { gi = s3; gf = s2; gg = s1; go = v;  }
    float cnew = sigm(gf) * c + sigm(gi) * tanh_(gg);
    c = cnew;
    return sigm(go) * tanh_(cnew);
}

// packed 4B agent-scope write-through stores of (hi_d, hi_{d+1}) and (lo_d, lo_{d+1})
DEVI void store_h_pair(float hnew, int r, unsigned short* __restrict__ hnh,
                       unsigned short* __restrict__ hnl, size_t o_even) {
    unsigned short hi = f2bf(hnew);
    float lo = hnew - bf2f(hi);
    float hp = __shfl_xor(hnew, 4, 64);   // partner lane: d ^ 1, same gate
    unsigned short hip = f2bf(hp);
    float lop = hp - bf2f(hip);
    if ((r & 7) == 0) {
        unsigned pk = (unsigned)hi | ((unsigned)hip << 16);
        __hip_atomic_store((unsigned*)(hnh + o_even), pk, __ATOMIC_RELAXED, __HIP_MEMORY_SCOPE_AGENT);
    } else if ((r & 7) == 1) {
        unsigned pk = (unsigned)f2bf(lo) | ((unsigned)f2bf(lop) << 16);
        __hip_atomic_store((unsigned*)(hnl + o_even), pk, __ATOMIC_RELAXED, __HIP_MEMORY_SCOPE_AGENT);
    }
}

DEVI void run_encoder(const CoopArgs& a, float (*smx)[160]) {
    int bid = blockIdx.x;
    int dir = bid >> 7, mb = (bid >> 4) & 7, nb = bid & 15;
    int tid = threadIdx.x, w = tid >> 6, lane = tid & 63, q = lane >> 4, r = lane & 15;
    int m0 = mb * 32;
    const unsigned short* __restrict__ whi = dir ? a.whb_hi : a.whf_hi;
    const unsigned short* __restrict__ wlo = dir ? a.whb_lo : a.whf_lo;
    const float* __restrict__ wxp = dir ? a.wxp_eb : a.wxp_ef;
    const float* __restrict__ bp = dir ? a.bp_eb : a.bp_ef;
    unsigned short* __restrict__ hhi = dir ? a.hb_hi : a.hf_hi;
    unsigned short* __restrict__ hlo = dir ? a.hb_lo : a.hf_lo;
    int grp = dir * 8 + mb;

    int c = nb * 64 + w * 16 + r;
    int g = r & 3, d = c >> 2;
    size_t d_even = (size_t)(d & ~1);

    short8 bh[8], bl[8];
#pragma unroll
    for (int ki = 0; ki < 8; ki++) {
        bh[ki] = *(const short8*)(whi + (size_t)c * H + ki * 32 + q * 8);
        bl[ki] = *(const short8*)(wlo + (size_t)c * H + ki * 32 + q * 8);
    }
    float wx0 = wxp[0 * 1024 + c], wx1 = wxp[1 * 1024 + c], wx2 = wxp[2 * 1024 + c];
    float wx3 = wxp[3 * 1024 + c], wx4 = wxp[4 * 1024 + c];
    float bias = bp[c];
    float creg[2][4];
#pragma unroll
    for (int mi = 0; mi < 2; mi++)
#pragma unroll
        for (int rr = 0; rr < 4; rr++) creg[mi][rr] = 0.f;

    // stage x(t=0) into LDS buf 0
    {
        int tt0 = dir ? 250 : 1;
        if (tid < 32) {
            const float* p = a.data + (size_t)(m0 + tid) * (5 * (T + 1)) + (size_t)tt0 * 5;
#pragma unroll
            for (int j = 0; j < 5; j++) smx[0][tid * 5 + j] = p[j];
        }
    }
    __syncthreads();

    for (int t = 0; t < T; t++) {
        int pi = t & 1;
        const unsigned short* __restrict__ hph = hhi + (size_t)pi * B * H;
        const unsigned short* __restrict__ hpl = hlo + (size_t)pi * B * H;
        f32x4 acc0 = {0.f, 0.f, 0.f, 0.f}, acc1 = {0.f, 0.f, 0.f, 0.f};
#pragma unroll
        for (int ki = 0; ki < 8; ki++) {
            int kb = ki * 32 + q * 8;
            short8 a0h = *(const short8*)(hph + (size_t)(m0 + r) * H + kb);
            short8 a1h = *(const short8*)(hph + (size_t)(m0 + 16 + r) * H + kb);
            short8 a0l = *(const short8*)(hpl + (size_t)(m0 + r) * H + kb);
            short8 a1l = *(const short8*)(hpl + (size_t)(m0 + 16 + r) * H + kb);
            acc0 = __builtin_amdgcn_mfma_f32_16x16x32_bf16(a0h, bh[ki], acc0, 0, 0, 0);
            acc1 = __builtin_amdgcn_mfma_f32_16x16x32_bf16(a1h, bh[ki], acc1, 0, 0, 0);
            acc0 = __builtin_amdgcn_mfma_f32_16x16x32_bf16(a0l, bh[ki], acc0, 0, 0, 0);
            acc1 = __builtin_amdgcn_mfma_f32_16x16x32_bf16(a1l, bh[ki], acc1, 0, 0, 0);
            acc0 = __builtin_amdgcn_mfma_f32_16x16x32_bf16(a0h, bl[ki], acc0, 0, 0, 0);
            acc1 = __builtin_amdgcn_mfma_f32_16x16x32_bf16(a1h, bl[ki], acc1, 0, 0, 0);
        }
        // prefetch x(t+1) into the other LDS buffer (overlaps epilogue)
        if (t + 1 < T && tid < 32) {
            int ttn = dir ? (249 - t) : (2 + t);
            const float* p = a.data + (size_t)(m0 + tid) * (5 * (T + 1)) + (size_t)ttn * 5;
#pragma unroll
            for (int j = 0; j < 5; j++) smx[(t + 1) & 1][tid * 5 + j] = p[j];
        }
        unsigned short* __restrict__ hnh = hhi + (size_t)(1 - pi) * B * H;
        unsigned short* __restrict__ hnl = hlo + (size_t)(1 - pi) * B * H;
        const float* xb = smx[t & 1];
#pragma unroll
        for (int mi = 0; mi < 2; mi++) {
            f32x4 acc = mi ? acc1 : acc0;
#pragma unroll
            for (int rr = 0; rr < 4; rr++) {
                int brow = mi * 16 + q * 4 + rr;
                float v = acc[rr] + bias + xb[brow * 5 + 0] * wx0 + xb[brow * 5 + 1] * wx1 +
                          xb[brow * 5 + 2] * wx2 + xb[brow * 5 + 3] * wx3 + xb[brow * 5 + 4] * wx4;
                float hnew = lstm_quad(v, g, creg[mi][rr]);
                store_h_pair(hnew, r, hnh, hnl, (size_t)(m0 + brow) * H + d_even);
            }
        }
        group_barrier(a.flags, a.go, grp, nb, 16, (unsigned)(t + 1));
    }
}

DEVI void run_decoder(const CoopArgs& a, float (*smx)[160]) {
    int bid = blockIdx.x;
    int mb = bid >> 5, nb = bid & 31;
    int tid = threadIdx.x, w = tid >> 6, lane = tid & 63, q = lane >> 4, r = lane & 15;
    int m0 = mb * 32;
    int grp = 16 + mb;

    int c = nb * 64 + w * 16 + r;
    int g = r & 3, d = c >> 2;
    size_t d_even = (size_t)(d & ~1);

    short8 bh[16], bl[16];
#pragma unroll
    for (int ki = 0; ki < 16; ki++) {
        bh[ki] = *(const short8*)(a.whd_hi + (size_t)c * D + ki * 32 + q * 8);
        bl[ki] = *(const short8*)(a.whd_lo + (size_t)c * D + ki * 32 + q * 8);
    }
    float wx0 = a.wxp_dec[0 * 2048 + c], wx1 = a.wxp_dec[1 * 2048 + c], wx2 = a.wxp_dec[2 * 2048 + c];
    float wx3 = a.wxp_dec[3 * 2048 + c], wx4 = a.wxp_dec[4 * 2048 + c];
    float zgc[2][4], creg[2][4];
#pragma unroll
    for (int mi = 0; mi < 2; mi++)
#pragma unroll
        for (int rr = 0; rr < 4; rr++) {
            int b = m0 + mi * 16 + q * 4 + rr;
            zgc[mi][rr] = a.zg[(size_t)b * 2048 + c];
            creg[mi][rr] = a.c32_d[(size_t)b * D + d];
        }

    if (tid < 32) {
        const float* p = a.data + (size_t)(m0 + tid) * (5 * (T + 1));
#pragma unroll
        for (int j = 0; j < 5; j++) smx[0][tid * 5 + j] = p[j];
    }
    __syncthreads();

    for (int t = 0; t < T; t++) {
        int pi = t & 1;
        const unsigned short* __restrict__ hph = a.hs_hi + (size_t)t * B * D;
        const unsigned short* __restrict__ hpl = a.hlo_pp + (size_t)pi * B * D;
        f32x4 acc0 = {0.f, 0.f, 0.f, 0.f}, acc1 = {0.f, 0.f, 0.f, 0.f};
#pragma unroll
        for (int ki = 0; ki < 16; ki++) {
            int kb = ki * 32 + q * 8;
            short8 a0h = *(const short8*)(hph + (size_t)(m0 + r) * D + kb);
            short8 a1h = *(const short8*)(hph + (size_t)(m0 + 16 + r) * D + kb);
            short8 a0l = *(const short8*)(hpl + (size_t)(m0 + r) * D + kb);
            short8 a1l = *(const short8*)(hpl + (size_t)(m0 + 16 + r) * D + kb);
            acc0 = __builtin_amdgcn_mfma_f32_16x16x32_bf16(a0h, bh[ki], acc0, 0, 0, 0);
            acc1 = __builtin_amdgcn_mfma_f32_16x16x32_bf16(a1h, bh[ki], acc1, 0, 0, 0);
            acc0 = __builtin_amdgcn_mfma_f32_16x16x32_bf16(a0l, bh[ki], acc0, 0, 0, 0);
            acc1 = __builtin_amdgcn_mfma_f32_16x16x32_bf16(a1l, bh[ki], acc1, 0, 0, 0);
            acc0 = __builtin_amdgcn_mfma_f32_16x16x32_bf16(a0h, bl[ki], acc0, 0, 0, 0);
            acc1 = __builtin_amdgcn_mfma_f32_16x16x32_bf16(a1h, bl[ki], acc1, 0, 0, 0);
        }
        if (t + 1 < T && tid < 32) {
            const float* p = a.data + (size_t)(m0 + tid) * (5 * (T + 1)) + (size_t)(t + 1) * 5;
#pragma unroll
            for (int j = 0; j < 5; j++) smx[(t + 1) & 1][tid * 5 + j] = p[j];
        }
        unsigned short* __restrict__ hnh = a.hs_hi + (size_t)(t + 1) * B * D;
        unsigned short* __restrict__ hnl = a.hlo_pp + (size_t)(1 - pi) * B * D;
        const float* xb = smx[t & 1];
#pragma unroll
        for (int mi = 0; mi < 2; mi++) {
            f32x4 acc = mi ? acc1 : acc0;
#pragma unroll
            for (int rr = 0; rr < 4; rr++) {
                int brow = mi * 16 + q * 4 + rr;
                float v = acc[rr] + zgc[mi][rr] + xb[brow * 5 + 0] * wx0 + xb[brow * 5 + 1] * wx1 +
                          xb[brow * 5 + 2] * wx2 + xb[brow * 5 + 3] * wx3 + xb[brow * 5 + 4] * wx4;
                float hnew = lstm_quad(v, g, creg[mi][rr]);
                store_h_pair(hnew, r, hnh, hnl, (size_t)(m0 + brow) * D + d_even);
            }
        }
        group_barrier(a.flags, a.go, grp, nb, 32, (unsigned)(t + 1));
    }
}

DEVI void run_encout(const CoopArgs& a, float* smem) {
    int b = blockIdx.x, tid = threadIdx.x;
    // final encoder h is in ping-pong slot 0 (T=250 even)
    if (tid < 128) {
        smem[tid]       = bf2f(a.hf_hi[(size_t)b * H + tid])       + bf2f(a.hf_lo[(size_t)b * H + tid]);
        smem[tid + 128] = bf2f(a.hf_hi[(size_t)b * H + tid + 128]) + bf2f(a.hf_lo[(size_t)b * H + tid + 128]);
        smem[tid + 256] = bf2f(a.hb_hi[(size_t)b * H + tid])       + bf2f(a.hb_lo[(size_t)b * H + tid]);
        smem[tid + 384] = bf2f(a.hb_hi[(size_t)b * H + tid + 128]) + bf2f(a.hb_lo[(size_t)b * H + tid + 128]);
    }
    __syncthreads();
    if (tid < 128) {
        float mean = a.eob[tid], lv = a.eob[Z + tid];
        for (int k = 0; k < 2 * H; k++) {
            float h = smem[k];
            mean += h * a.eoW[(size_t)k * 2 * Z + tid];
            lv += h * a.eoW[(size_t)k * 2 * Z + Z + tid];
        }
        float z = mean + __expf(0.5f * lv) * a.eps[(size_t)b * Z + tid];
        a.out[OUT_ZM + (size_t)b * Z + tid] = mean;
        a.out[OUT_ZL + (size_t)b * Z + tid] = lv;
        a.zbuf[(size_t)b * Z + tid] = z;
    }
    __syncthreads();
}

DEVI void run_init_zg(const CoopArgs& a, float* smem) {
    int bid = blockIdx.x, tid = threadIdx.x;
    if (bid < 64) {
        int cc = (bid & 3) * 256 + tid;
        int b0 = (bid >> 2) * 16;
        for (int i = tid; i < 16 * Z; i += 256)
            smem[i] = a.zbuf[(size_t)(b0 + (i >> 7)) * Z + (i & 127)];
        __syncthreads();
        float acc[16];
        float bias = a.ib[cc];
#pragma unroll
        for (int bb = 0; bb < 16; bb++) acc[bb] = bias;
        for (int k = 0; k < Z; k++) {
            float wv = a.iW[(size_t)k * 1024 + cc];
#pragma unroll
            for (int bb = 0; bb < 16; bb++) acc[bb] += smem[bb * 128 + k] * wv;
        }
        for (int bb = 0; bb < 16; bb++) {
            float v = tanh_(acc[bb]);
            int b = b0 + bb;
            if (cc < D) {
                unsigned short hi = f2bf(v);
                a.hs_hi[(size_t)b * D + cc] = hi;
                a.hlo_pp[(size_t)b * D + cc] = f2bf(v - bf2f(hi));
            } else {
                a.c32_d[(size_t)b * D + (cc - D)] = v;
            }
        }
    } else if (bid < 192) {
        int bid2 = bid - 64;
        int cc = (bid2 & 7) * 256 + tid;
        int b0 = (bid2 >> 3) * 16;
        for (int i = tid; i < 16 * Z; i += 256)
            smem[i] = a.zbuf[(size_t)(b0 + (i >> 7)) * Z + (i & 127)];
        __syncthreads();
        float acc[16];
        float db_c = a.db[cc];
#pragma unroll
        for (int bb = 0; bb < 16; bb++) acc[bb] = db_c;
        for (int k = 0; k < Z; k++) {
            float wv = a.dWx[(size_t)(5 + k) * 2048 + cc];
#pragma unroll
            for (int bb = 0; bb < 16; bb++) acc[bb] += smem[bb * 128 + k] * wv;
        }
        int n = 4 * (cc & 511) + (cc >> 9);
#pragma unroll
        for (int bb = 0; bb < 16; bb++) a.zg[(size_t)(b0 + bb) * 2048 + n] = acc[bb];
    }
    __syncthreads();
}

__global__ __launch_bounds__(256, 1) void k_coop(CoopArgs a) {
    __shared__ float smem[2048];
    __shared__ float smx[2][160];
    run_encoder(a, smx);
    cg::this_grid().sync();
    run_encout(a, smem);
    cg::this_grid().sync();
    run_init_zg(a, smem);
    cg::this_grid().sync();
    run_decoder(a, smx);
}

// ---------------- mix GEMM ----------------
__global__ __launch_bounds__(256) void k_mix(const unsigned short* __restrict__ hs,
                                             const unsigned short* __restrict__ mixwt,
                                             const float* __restrict__ mb, float* __restrict__ dout) {
    int tid = threadIdx.x, wave = tid >> 6, lane = tid & 63, q = lane >> 4, r = lane & 15;
    int m0 = blockIdx.y * 64 + (wave >> 1) * 32;
    int n0 = blockIdx.x * 64 + (wave & 1) * 32;
    const unsigned short* A = hs + (size_t)B * D;  // ring slots 1..T
    f32x4 acc[2][2];
#pragma unroll
    for (int mi = 0; mi < 2; mi++)
#pragma unroll
        for (int ni = 0; ni < 2; ni++) acc[mi][ni] = {0.f, 0.f, 0.f, 0.f};
#pragma unroll 4
    for (int kk = 0; kk < D; kk += 32) {
        int kb = kk + q * 8;
        short8 a0 = *(const short8*)(A + (size_t)(m0 + r) * D + kb);
        short8 a1 = *(const short8*)(A + (size_t)(m0 + 16 + r) * D + kb);
        short8 b0 = *(const short8*)(mixwt + (size_t)(n0 + r) * D + kb);
        short8 b1 = *(const short8*)(mixwt + (size_t)(n0 + 16 + r) * D + kb);
        acc[0][0] = __builtin_amdgcn_mfma_f32_16x16x32_bf16(a0, b0, acc[0][0], 0, 0, 0);
        acc[0][1] = __builtin_amdgcn_mfma_f32_16x16x32_bf16(a0, b1, acc[0][1], 0, 0, 0);
        acc[1][0] = __builtin_amdgcn_mfma_f32_16x16x32_bf16(a1, b0, acc[1][0], 0, 0, 0);
        acc[1][1] = __builtin_amdgcn_mfma_f32_16x16x32_bf16(a1, b1, acc[1][1], 0, 0, 0);
    }
#pragma unroll
    for (int ni = 0; ni < 2; ni++) {
        int ncol = n0 + ni * 16 + r;
        if (ncol < P) {
            float bias = mb[ncol];
#pragma unroll
            for (int mi = 0; mi < 2; mi++) {
#pragma unroll
                for (int rr = 0; rr < 4; rr++) {
                    int m = m0 + mi * 16 + q * 4 + rr;
                    int b = m & 255, t = m >> 8;
                    dout[((size_t)b * T + t) * P + ncol] = acc[mi][ni][rr] + bias;
                }
            }
        }
    }
}

// ---------------- per-row epilogue ----------------
__global__ void k_post(float* __restrict__ dout) {
    __shared__ float row[P];
    int rid = blockIdx.x;
    int tid = threadIdx.x;
    float* base = dout + (size_t)rid * P;
    float v = 0.f;
    if (tid < P) { v = base[tid]; row[tid] = v; }
    __syncthreads();
    if (tid < P) {
        float o;
        if (tid < KMIX) {
            float mx = row[0];
            for (int i = 1; i < KMIX; i++) mx = fmaxf(mx, row[i]);
            float sm = 0.f;
            for (int i = 0; i < KMIX; i++) sm += __expf(row[i] - mx);
            o = __expf(v - mx) / sm;
        } else if (tid < 3 * KMIX) o = v;
        else if (tid < 5 * KMIX) o = __expf(v);
        else if (tid < 6 * KMIX) o = tanh_(v);
        else o = v;
        base[tid] = o;
    }
}

extern "C" void kernel_launch(void* const* d_in, const int* in_sizes, int n_in,
                              void* d_out, int out_size, void* d_ws, size_t ws_size,
                              hipStream_t stream) {
    const float* data = (const float*)d_in[0];
    const float* eps  = (const float*)d_in[1];
    const float* eWxf = (const float*)d_in[2];
    const float* eWhf = (const float*)d_in[3];
    const float* ebf  = (const float*)d_in[4];
    const float* eWxb = (const float*)d_in[5];
    const float* eWhb = (const float*)d_in[6];
    const float* ebb  = (const float*)d_in[7];
    const float* eoW  = (const float*)d_in[8];
    const float* eob  = (const float*)d_in[9];
    const float* iW   = (const float*)d_in[10];
    const float* ib   = (const float*)d_in[11];
    const float* dWx  = (const float*)d_in[12];
    const float* dWh  = (const float*)d_in[13];
    const float* db   = (const float*)d_in[14];
    const float* mW   = (const float*)d_in[15];
    const float* mb   = (const float*)d_in[16];
    float* out = (float*)d_out;

    char* base = (char*)d_ws;
    size_t off = 0;
    auto alloc = [&](size_t bytes) -> char* {
        off = (off + 255) & ~(size_t)255;
        char* p = base + off;
        off += bytes;
        return p;
    };
    unsigned short* whd_hi = (unsigned short*)alloc((size_t)2048 * 512 * 2);
    unsigned short* whd_lo = (unsigned short*)alloc((size_t)2048 * 512 * 2);
    unsigned short* whf_hi = (unsigned short*)alloc((size_t)1024 * 256 * 2);
    unsigned short* whf_lo = (unsigned short*)alloc((size_t)1024 * 256 * 2);
    unsigned short* whb_hi = (unsigned short*)alloc((size_t)1024 * 256 * 2);
    unsigned short* whb_lo = (unsigned short*)alloc((size_t)1024 * 256 * 2);
    unsigned short* mixwt  = (unsigned short*)alloc((size_t)128 * 512 * 2);
    float* wxp_dec = (float*)alloc((size_t)5 * 2048 * 4);
    float* wxp_ef  = (float*)alloc((size_t)5 * 1024 * 4);
    float* wxp_eb  = (float*)alloc((size_t)5 * 1024 * 4);
    float* bp_ef   = (float*)alloc((size_t)1024 * 4);
    float* bp_eb   = (float*)alloc((size_t)1024 * 4);
    unsigned short* hf_hi = (unsigned short*)alloc((size_t)2 * B * H * 2);
    unsigned short* hf_lo = (unsigned short*)alloc((size_t)2 * B * H * 2);
    unsigned short* hb_hi = (unsigned short*)alloc((size_t)2 * B * H * 2);
    unsigned short* hb_lo = (unsigned short*)alloc((size_t)2 * B * H * 2);
    float* c32_d  = (float*)alloc((size_t)B * D * 4);
    unsigned short* hs_hi = (unsigned short*)alloc((size_t)(T + 1) * B * D * 2);
    unsigned short* hlo_pp = (unsigned short*)alloc((size_t)2 * B * D * 2);
    float* zbuf = (float*)alloc((size_t)B * Z * 4);
    float* zg   = (float*)alloc((size_t)B * 2048 * 4);
    unsigned* flags = (unsigned*)alloc((size_t)24 * 1024 * 4);
    unsigned* go    = (unsigned*)alloc((size_t)24 * 32 * 4);
    (void)ws_size; (void)in_sizes; (void)n_in; (void)out_size;

    k_zero<<<256, 256, 0, stream>>>(hf_hi, hb_hi, hf_lo, hb_lo, flags, go);
    k_pack_whT<512><<<dim3(64, 16), dim3(32, 8), 0, stream>>>(dWh, whd_hi, whd_lo);
    k_pack_whT<256><<<dim3(32, 8), dim3(32, 8), 0, stream>>>(eWhf, whf_hi, whf_lo);
    k_pack_whT<256><<<dim3(32, 8), dim3(32, 8), 0, stream>>>(eWhb, whb_hi, whb_lo);
    k_pack_mix<<<256, 256, 0, stream>>>(mW, mixwt);
    k_pack_cols<<<40, 256, 0, stream>>>(dWx, wxp_dec, 512, 2048);
    k_pack_cols<<<20, 256, 0, stream>>>(eWxf, wxp_ef, 256, 1024);
    k_pack_cols<<<20, 256, 0, stream>>>(eWxb, wxp_eb, 256, 1024);
    k_pack_cols<<<4, 256, 0, stream>>>(ebf, bp_ef, 256, 1024);
    k_pack_cols<<<4, 256, 0, stream>>>(ebb, bp_eb, 256, 1024);

    CoopArgs ca;
    ca.data = data; ca.eps = eps;
    ca.whf_hi = whf_hi; ca.whf_lo = whf_lo; ca.whb_hi = whb_hi; ca.whb_lo = whb_lo;
    ca.whd_hi = whd_hi; ca.whd_lo = whd_lo;
    ca.wxp_ef = wxp_ef; ca.wxp_eb = wxp_eb; ca.wxp_dec = wxp_dec;
    ca.bp_ef = bp_ef; ca.bp_eb = bp_eb;
    ca.eoW = eoW; ca.eob = eob; ca.iW = iW; ca.ib = ib; ca.dWx = dWx; ca.db = db;
    ca.hf_hi = hf_hi; ca.hf_lo = hf_lo; ca.hb_hi = hb_hi; ca.hb_lo = hb_lo;
    ca.c32_d = c32_d;
    ca.hs_hi = hs_hi; ca.hlo_pp = hlo_pp;
    ca.zbuf = zbuf; ca.zg = zg; ca.out = out;
    ca.flags = flags; ca.go = go;

    void* kp[] = { &ca };
    hipLaunchCooperativeKernel((void*)k_coop, dim3(256), dim3(256), kp, 0, stream);

    k_mix<<<dim3(2, 1000), 256, 0, stream>>>(hs_hi, mixwt, mb, out);
    k_post<<<64000, 128, 0, stream>>>(out);
}